// Round 1
// baseline (678.065 us; speedup 1.0000x reference)
//
#include <hip/hip_runtime.h>

// GCN forward on MI355X. fp32 baseline, CSR-gather aggregation.
// Pipeline:
//   deg/dis -> CSR build (scan + fill) ->
//   X1 = lrelu(MF@W_in + b_in)               [gemm K=128, EPI_LRELU]
//   H1s = (X1@Wg1) * dis[row]                [gemm K=256, EPI_SCALE]
//   X2 = dis[d]*(H1s[d] + sum_nbr H1s[s]) + bg1   [agg]
//   H2s = (X2@Wg2) * dis[row]                [gemm K=256, EPI_SCALE]
//   X3 = agg(H2s) + bg2                      [agg]
//   M1 = lrelu((F-MF)@W_in + b_in)           [gemm K=128, EPI_SUB_LRELU]
//   out = (X3@Wo + bo) * (M1@Wo + bo)        [final]

#define NEG_SLOPE 0.01f
constexpr int HD = 256; // GEMM output width (H_DIM), fixed

// ---------------- graph preprocessing ----------------
__global__ void k_deginit(int* __restrict__ deg, int N) {
  int i = blockIdx.x * 256 + threadIdx.x;
  if (i < N) deg[i] = 1; // self-loop
}

__global__ void k_deg(const int* __restrict__ dst, int* __restrict__ deg, int E) {
  int e = blockIdx.x * 256 + threadIdx.x;
  if (e < E) atomicAdd(&deg[dst[e]], 1);
}

__global__ void k_dis(const int* __restrict__ deg, float* __restrict__ dis, int N) {
  int i = blockIdx.x * 256 + threadIdx.x;
  if (i < N) dis[i] = rsqrtf((float)deg[i]);
}

// exclusive scan of (deg[i]-1) over N elements, 3-kernel hierarchy
__global__ __launch_bounds__(1024) void k_scan1(const int* __restrict__ deg,
                                                int* __restrict__ rp,
                                                int* __restrict__ sums, int N) {
  const int i = blockIdx.x * 1024 + threadIdx.x;
  const int lane = threadIdx.x & 63;
  const int wid = threadIdx.x >> 6;
  int v = (i < N) ? (deg[i] - 1) : 0;
  int incl = v;
  #pragma unroll
  for (int o = 1; o < 64; o <<= 1) {
    int t = __shfl_up(incl, o, 64);
    if (lane >= o) incl += t;
  }
  __shared__ int ws[16];
  if (lane == 63) ws[wid] = incl;
  __syncthreads();
  if (threadIdx.x == 0) {
    int run = 0;
    #pragma unroll
    for (int w = 0; w < 16; ++w) { int t = ws[w]; ws[w] = run; run += t; }
    sums[blockIdx.x] = run;
  }
  __syncthreads();
  if (i < N) rp[i] = incl - v + ws[wid];
}

__global__ void k_scan2(int* __restrict__ sums, int nb) {
  int lane = threadIdx.x; // blockDim = 64, nb <= 64
  int v = (lane < nb) ? sums[lane] : 0;
  int incl = v;
  #pragma unroll
  for (int o = 1; o < 64; o <<= 1) {
    int t = __shfl_up(incl, o, 64);
    if (lane >= o) incl += t;
  }
  if (lane < nb) sums[lane] = incl - v; // exclusive block offsets
}

__global__ void k_scan3(int* __restrict__ rp, int* __restrict__ cur,
                        const int* __restrict__ sums, int N, int E) {
  int i = blockIdx.x * 256 + threadIdx.x;
  if (i < N) {
    int v = rp[i] + sums[i >> 10];
    rp[i] = v;
    cur[i] = v;
  }
  if (i == 0) rp[N] = E;
}

__global__ void k_fill(const int* __restrict__ src, const int* __restrict__ dst,
                       int* __restrict__ cur, int* __restrict__ csr, int E) {
  int e = blockIdx.x * 256 + threadIdx.x;
  if (e < E) {
    int d = dst[e];
    int pos = atomicAdd(&cur[d], 1);
    csr[pos] = src[e];
  }
}

// ---------------- GEMM: C[M,256] = epi(A[M,K] @ W[K,256]) ----------------
enum { EPI_LRELU = 0, EPI_SCALE = 1, EPI_SUB_LRELU = 2 };

template <int K, int EPI>
__global__ __launch_bounds__(256) void k_gemm(
    const float* __restrict__ A, const float* __restrict__ A2,
    const float* __restrict__ W, const float* __restrict__ bias,
    const float* __restrict__ scale, float* __restrict__ C, int M) {
  constexpr int BM = 128, BN = 128, BK = 16;
  __shared__ float As[BK][BM + 4]; // k-major, pad keeps b128 reads conflict-free & aligned
  __shared__ float Bs[BK][BN + 4];
  const int tid = threadIdx.x;
  const int tx = tid & 15, ty = tid >> 4;
  const int bm = blockIdx.x * BM, bn = blockIdx.y * BN;
  const int m0 = ty * 8, n0 = tx * 8;

  float acc[8][8];
  #pragma unroll
  for (int i = 0; i < 8; ++i)
    #pragma unroll
    for (int j = 0; j < 8; ++j) acc[i][j] = 0.f;

  for (int kt = 0; kt < K; kt += BK) {
    // A tile: 128 rows x 16 k, two float4 per thread, store transposed (k-major)
    #pragma unroll
    for (int p = 0; p < 2; ++p) {
      int idx = tid + p * 256;  // 0..511
      int ar = idx >> 2;        // 0..127
      int ac = (idx & 3) * 4;   // 0,4,8,12
      int gr = bm + ar;
      if (gr >= M) gr = M - 1; // clamp; stores are guarded
      float4 v = *(const float4*)&A[(size_t)gr * K + kt + ac];
      if constexpr (EPI == EPI_SUB_LRELU) {
        float4 v2 = *(const float4*)&A2[(size_t)gr * K + kt + ac];
        v.x -= v2.x; v.y -= v2.y; v.z -= v2.z; v.w -= v2.w;
      }
      As[ac + 0][ar] = v.x;
      As[ac + 1][ar] = v.y;
      As[ac + 2][ar] = v.z;
      As[ac + 3][ar] = v.w;
    }
    // B tile: 16 k x 128 n
    #pragma unroll
    for (int p = 0; p < 2; ++p) {
      int idx = tid + p * 256;  // 0..511
      int br = idx >> 5;        // 0..15
      int bc = (idx & 31) * 4;  // 0..124
      *(float4*)&Bs[br][bc] = *(const float4*)&W[(size_t)(kt + br) * HD + bn + bc];
    }
    __syncthreads();
    #pragma unroll
    for (int k = 0; k < BK; ++k) {
      float4 A0 = *(const float4*)&As[k][m0];
      float4 A1 = *(const float4*)&As[k][m0 + 4];
      float4 B0 = *(const float4*)&Bs[k][n0];
      float4 B1 = *(const float4*)&Bs[k][n0 + 4];
      float aa[8] = {A0.x, A0.y, A0.z, A0.w, A1.x, A1.y, A1.z, A1.w};
      float bb[8] = {B0.x, B0.y, B0.z, B0.w, B1.x, B1.y, B1.z, B1.w};
      #pragma unroll
      for (int i = 0; i < 8; ++i)
        #pragma unroll
        for (int j = 0; j < 8; ++j) acc[i][j] = fmaf(aa[i], bb[j], acc[i][j]);
    }
    __syncthreads();
  }

  #pragma unroll
  for (int i = 0; i < 8; ++i) {
    int row = bm + m0 + i;
    if (row < M) {
      float v[8];
      #pragma unroll
      for (int j = 0; j < 8; ++j) v[j] = acc[i][j];
      if constexpr (EPI == EPI_SCALE) {
        float s = scale[row];
        #pragma unroll
        for (int j = 0; j < 8; ++j) v[j] *= s;
      } else {
        #pragma unroll
        for (int j = 0; j < 8; ++j) {
          float t = v[j] + bias[bn + n0 + j];
          v[j] = t > 0.f ? t : NEG_SLOPE * t;
        }
      }
      float* cp = &C[(size_t)row * HD + bn + n0];
      *(float4*)cp = make_float4(v[0], v[1], v[2], v[3]);
      *(float4*)(cp + 4) = make_float4(v[4], v[5], v[6], v[7]);
    }
  }
}

// ---------------- aggregation: out[d,:] = dis[d]*(H[d,:] + sum_s H[s,:]) + bias ---
__global__ __launch_bounds__(256) void k_agg(
    const float* __restrict__ H, const int* __restrict__ rp,
    const int* __restrict__ csr, const float* __restrict__ dis,
    const float* __restrict__ bias, float* __restrict__ out) {
  const int n = blockIdx.x;
  const int t = threadIdx.x;
  const int s0 = rp[n], s1 = rp[n + 1];
  __shared__ int eid[256];
  float acc = H[(size_t)n * HD + t]; // self-loop term (H already scaled by dis[n])
  int cnt = s1 - s0;
  for (int base = 0; base < cnt; base += 256) {
    int m = cnt - base;
    if (m > 256) m = 256;
    __syncthreads();
    if (t < m) eid[t] = csr[s0 + base + t];
    __syncthreads();
    for (int e = 0; e < m; ++e) {
      acc += H[(size_t)eid[e] * HD + t];
    }
  }
  out[(size_t)n * HD + t] = acc * dis[n] + bias[t];
}

// ---------------- final: out[n,j] = (X3[n,:]·Wo[:,j]+bo[j]) * (M1[n,:]·Wo[:,j]+bo[j])
__global__ __launch_bounds__(256) void k_final(
    const float* __restrict__ X, const float* __restrict__ Mm,
    const float* __restrict__ Wo, const float* __restrict__ bo,
    float* __restrict__ out, int M) {
  int wave = threadIdx.x >> 6;
  int lane = threadIdx.x & 63;
  int n = blockIdx.x * 4 + wave;
  if (n >= M) return;
  float x0 = 0.f, x1 = 0.f, m0 = 0.f, m1 = 0.f;
  #pragma unroll
  for (int q = 0; q < 4; ++q) {
    int k = q * 64 + lane;
    float xv = X[(size_t)n * HD + k];
    float mv = Mm[(size_t)n * HD + k];
    float w0 = Wo[k * 2 + 0];
    float w1 = Wo[k * 2 + 1];
    x0 = fmaf(xv, w0, x0);
    x1 = fmaf(xv, w1, x1);
    m0 = fmaf(mv, w0, m0);
    m1 = fmaf(mv, w1, m1);
  }
  #pragma unroll
  for (int o = 32; o > 0; o >>= 1) {
    x0 += __shfl_down(x0, o);
    x1 += __shfl_down(x1, o);
    m0 += __shfl_down(m0, o);
    m1 += __shfl_down(m1, o);
  }
  if (lane == 0) {
    float b0 = bo[0], b1 = bo[1];
    out[(size_t)n * 2 + 0] = (x0 + b0) * (m0 + b0);
    out[(size_t)n * 2 + 1] = (x1 + b1) * (m1 + b1);
  }
}

extern "C" void kernel_launch(void* const* d_in, const int* in_sizes, int n_in,
                              void* d_out, int out_size, void* d_ws, size_t ws_size,
                              hipStream_t stream) {
  const float* mf  = (const float*)d_in[0];
  const float* fe  = (const float*)d_in[1];
  const int*   ei  = (const int*)d_in[2];
  // d_in[3] edge_type: unused by reference
  const float* Win = (const float*)d_in[4];
  const float* bin = (const float*)d_in[5];
  const float* Wg1 = (const float*)d_in[6];
  const float* bg1 = (const float*)d_in[7];
  const float* Wg2 = (const float*)d_in[8];
  const float* bg2 = (const float*)d_in[9];
  const float* Wo  = (const float*)d_in[10];
  const float* bo  = (const float*)d_in[11];
  float* out = (float*)d_out;

  const int ED = 128;
  const int N = in_sizes[0] / ED;  // 50000
  const int E = in_sizes[3];       // 800000
  const int* src = ei;
  const int* dst = ei + E;

  char* ws = (char*)d_ws;
  size_t off = 0;
  auto carve = [&](size_t bytes) {
    char* p = ws + off;
    off += (bytes + 255) & ~(size_t)255;
    return p;
  };
  float* bufA = (float*)carve((size_t)N * HD * 4);
  float* bufB = (float*)carve((size_t)N * HD * 4);
  int*   deg  = (int*)carve((size_t)N * 4);
  float* dis  = (float*)carve((size_t)N * 4);
  int*   rp   = (int*)carve((size_t)(N + 1) * 4);
  int*   cur  = (int*)carve((size_t)N * 4);
  int*   csr  = (int*)carve((size_t)E * 4);
  int*   sums = (int*)carve(64 * 4);
  (void)ws_size; (void)n_in; (void)out_size;

  const int nb = (N + 1023) / 1024; // 49 <= 64

  // graph preprocessing
  k_deginit<<<(N + 255) / 256, 256, 0, stream>>>(deg, N);
  k_deg<<<(E + 255) / 256, 256, 0, stream>>>(dst, deg, E);
  k_dis<<<(N + 255) / 256, 256, 0, stream>>>(deg, dis, N);
  k_scan1<<<nb, 1024, 0, stream>>>(deg, rp, sums, N);
  k_scan2<<<1, 64, 0, stream>>>(sums, nb);
  k_scan3<<<(N + 255) / 256, 256, 0, stream>>>(rp, cur, sums, N, E);
  k_fill<<<(E + 255) / 256, 256, 0, stream>>>(src, dst, cur, csr, E);

  dim3 gg((N + 127) / 128, 2);
  // X1 = lrelu(MF @ W_in + b_in)
  k_gemm<128, EPI_LRELU><<<gg, 256, 0, stream>>>(mf, nullptr, Win, bin, nullptr, bufA, N);
  // H1s = (X1 @ Wg1) * dis[row]
  k_gemm<256, EPI_SCALE><<<gg, 256, 0, stream>>>(bufA, nullptr, Wg1, nullptr, dis, bufB, N);
  // X2 = agg(H1s) + bg1
  k_agg<<<N, 256, 0, stream>>>(bufB, rp, csr, dis, bg1, bufA);
  // H2s = (X2 @ Wg2) * dis[row]
  k_gemm<256, EPI_SCALE><<<gg, 256, 0, stream>>>(bufA, nullptr, Wg2, nullptr, dis, bufB, N);
  // X3 = agg(H2s) + bg2
  k_agg<<<N, 256, 0, stream>>>(bufB, rp, csr, dis, bg2, bufA);
  // M1 = lrelu((F - MF) @ W_in + b_in)
  k_gemm<128, EPI_SUB_LRELU><<<gg, 256, 0, stream>>>(fe, mf, Win, bin, nullptr, bufB, N);
  // out = (X3@Wo + bo) * (M1@Wo + bo)
  k_final<<<(N + 3) / 4, 256, 0, stream>>>(bufA, bufB, Wo, bo, out, N);
}

// Round 2
// 414.826 us; speedup vs baseline: 1.6346x; 1.6346x over previous
//
#include <hip/hip_runtime.h>

// GCN forward, algebraically collapsed.
// Key identity: everything after the first leaky-ReLU is linear, and
// Â = D^-1/2 (A+I) D^-1/2 commutes with right-mult by W. Hence:
//   Z_main = ÂÂ(X1) @ Wbig + (Â·1) ⊗ u + 1 ⊗ v
// where X1 = lrelu(MF@W_in+b_in), Wbig = Wg1@Wg2@W_out  [256,2],
//       u = bg1@Wg2@W_out [2], v = bg2@W_out + b_out [2].
// Mask branch: Pm = lrelu((F-MF)@W_in+b_in) @ W_out;  out = Z_main * (Pm + b_out).
// Aggregation runs on [N,2] data (L2-resident) via edge-parallel atomics.

#define NEG_SLOPE 0.01f
constexpr int HD = 256;

// ---------------- tiny utility kernels ----------------
__global__ void k_zero(float* __restrict__ p, int n) {
  int i = blockIdx.x * 256 + threadIdx.x;
  if (i < n) p[i] = 0.f;
}

__global__ void k_deginit(int* __restrict__ deg, int N) {
  int i = blockIdx.x * 256 + threadIdx.x;
  if (i < N) deg[i] = 1; // self-loop
}

__global__ void k_deg(const int* __restrict__ dst, int* __restrict__ deg, int E) {
  int e = blockIdx.x * 256 + threadIdx.x;
  if (e < E) atomicAdd(&deg[dst[e]], 1);
}

__global__ void k_dis(const int* __restrict__ deg, float* __restrict__ dis, int N) {
  int i = blockIdx.x * 256 + threadIdx.x;
  if (i < N) dis[i] = rsqrtf((float)deg[i]);
}

// adeg[d] += dis[src]  over edges
__global__ void k_adeg(const int* __restrict__ src, const int* __restrict__ dst,
                       const float* __restrict__ dis, float* __restrict__ adeg, int E) {
  int e = blockIdx.x * 256 + threadIdx.x;
  if (e < E) atomicAdd(&adeg[dst[e]], dis[src[e]]);
}

// a[n] = dis[n]*(dis[n] + adeg[n])   ( = (Â·1)[n] )
__global__ void k_a(const float* __restrict__ dis, const float* __restrict__ adeg,
                    float* __restrict__ a, int N) {
  int i = blockIdx.x * 256 + threadIdx.x;
  if (i < N) a[i] = dis[i] * (dis[i] + adeg[i]);
}

// Wbig = Wg1 @ (Wg2 @ Wo) [256,2]; uv = {u0,u1,v0,v1}
__global__ __launch_bounds__(256) void k_consts(
    const float* __restrict__ Wg1, const float* __restrict__ Wg2,
    const float* __restrict__ Wo, const float* __restrict__ bg1,
    const float* __restrict__ bg2, const float* __restrict__ bo,
    float* __restrict__ wb, float* __restrict__ uv) {
  __shared__ float wt[256][2];
  int r = threadIdx.x;
  float s0 = 0.f, s1 = 0.f;
  for (int k = 0; k < 256; ++k) {
    float w = Wg2[r * 256 + k];
    s0 = fmaf(w, Wo[k * 2 + 0], s0);
    s1 = fmaf(w, Wo[k * 2 + 1], s1);
  }
  wt[r][0] = s0; wt[r][1] = s1;
  __syncthreads();
  float b0 = 0.f, b1 = 0.f;
  for (int k = 0; k < 256; ++k) {
    float w = Wg1[r * 256 + k];
    b0 = fmaf(w, wt[k][0], b0);
    b1 = fmaf(w, wt[k][1], b1);
  }
  wb[r * 2 + 0] = b0; wb[r * 2 + 1] = b1;
  if (r < 2) {
    float u = 0.f, v = 0.f;
    for (int k = 0; k < 256; ++k) {
      u = fmaf(bg1[k], wt[k][r], u);
      v = fmaf(bg2[k], Wo[k * 2 + r], v);
    }
    uv[r] = u;          // u[c]
    uv[2 + r] = v + bo[r]; // v[c] = bg2@Wo + b_out
  }
}

// ---------------- fused GEMM + [256,2] reduction ----------------
// P[row,c] += sum_j lrelu(A[row,:]@W[:,col_j] + bias[col_j]) * wr[col_j,c]
enum { EPI_LRELU = 0, EPI_SUB_LRELU = 1 };

template <int EPI>
__global__ __launch_bounds__(256) void k_gemmr(
    const float* __restrict__ A, const float* __restrict__ A2,
    const float* __restrict__ W, const float* __restrict__ bias,
    const float* __restrict__ wr, float* __restrict__ P, int M) {
  constexpr int K = 128, BM = 128, BN = 128, BK = 16;
  __shared__ float As[BK][BM + 4];
  __shared__ float Bs[BK][BN + 4];
  const int tid = threadIdx.x;
  const int tx = tid & 15, ty = tid >> 4;
  const int bm = blockIdx.x * BM, bn = blockIdx.y * BN;
  const int m0 = ty * 8, n0 = tx * 8;

  float acc[8][8];
  #pragma unroll
  for (int i = 0; i < 8; ++i)
    #pragma unroll
    for (int j = 0; j < 8; ++j) acc[i][j] = 0.f;

  for (int kt = 0; kt < K; kt += BK) {
    #pragma unroll
    for (int p = 0; p < 2; ++p) {
      int idx = tid + p * 256;
      int ar = idx >> 2;
      int ac = (idx & 3) * 4;
      int gr = bm + ar;
      if (gr >= M) gr = M - 1;
      float4 v = *(const float4*)&A[(size_t)gr * K + kt + ac];
      if constexpr (EPI == EPI_SUB_LRELU) {
        float4 v2 = *(const float4*)&A2[(size_t)gr * K + kt + ac];
        v.x -= v2.x; v.y -= v2.y; v.z -= v2.z; v.w -= v2.w;
      }
      As[ac + 0][ar] = v.x;
      As[ac + 1][ar] = v.y;
      As[ac + 2][ar] = v.z;
      As[ac + 3][ar] = v.w;
    }
    #pragma unroll
    for (int p = 0; p < 2; ++p) {
      int idx = tid + p * 256;
      int br = idx >> 5;
      int bc = (idx & 31) * 4;
      *(float4*)&Bs[br][bc] = *(const float4*)&W[(size_t)(kt + br) * HD + bn + bc];
    }
    __syncthreads();
    #pragma unroll
    for (int k = 0; k < BK; ++k) {
      float4 A0 = *(const float4*)&As[k][m0];
      float4 A1 = *(const float4*)&As[k][m0 + 4];
      float4 B0 = *(const float4*)&Bs[k][n0];
      float4 B1 = *(const float4*)&Bs[k][n0 + 4];
      float aa[8] = {A0.x, A0.y, A0.z, A0.w, A1.x, A1.y, A1.z, A1.w};
      float bb[8] = {B0.x, B0.y, B0.z, B0.w, B1.x, B1.y, B1.z, B1.w};
      #pragma unroll
      for (int i = 0; i < 8; ++i)
        #pragma unroll
        for (int j = 0; j < 8; ++j) acc[i][j] = fmaf(aa[i], bb[j], acc[i][j]);
    }
    __syncthreads();
  }

  // epilogue: bias + lrelu, then reduce 8 cols against wr -> 2 partials per row
  float w0[8], w1[8], bb[8];
  #pragma unroll
  for (int j = 0; j < 8; ++j) {
    int col = bn + n0 + j;
    w0[j] = wr[col * 2 + 0];
    w1[j] = wr[col * 2 + 1];
    bb[j] = bias[col];
  }
  float p0[8], p1[8];
  #pragma unroll
  for (int i = 0; i < 8; ++i) {
    float s0 = 0.f, s1 = 0.f;
    #pragma unroll
    for (int j = 0; j < 8; ++j) {
      float t = acc[i][j] + bb[j];
      t = t > 0.f ? t : NEG_SLOPE * t;
      s0 = fmaf(t, w0[j], s0);
      s1 = fmaf(t, w1[j], s1);
    }
    p0[i] = s0; p1[i] = s1;
  }
  // reduce across the 16 tx-lanes (contiguous lanes within the wave)
  #pragma unroll
  for (int o = 1; o < 16; o <<= 1) {
    #pragma unroll
    for (int i = 0; i < 8; ++i) {
      p0[i] += __shfl_xor(p0[i], o, 16);
      p1[i] += __shfl_xor(p1[i], o, 16);
    }
  }
  if (tx == 0) {
    #pragma unroll
    for (int i = 0; i < 8; ++i) {
      int row = bm + m0 + i;
      if (row < M) {
        atomicAdd(&P[row * 2 + 0], p0[i]);
        atomicAdd(&P[row * 2 + 1], p1[i]);
      }
    }
  }
}

// ---------------- [N,2] aggregation passes ----------------
// T = dis * P
__global__ void k_pre(const float* __restrict__ dis, const float* __restrict__ P,
                      float* __restrict__ T, int N) {
  int i = blockIdx.x * 256 + threadIdx.x;
  if (i < N) {
    float d = dis[i];
    T[i * 2 + 0] = d * P[i * 2 + 0];
    T[i * 2 + 1] = d * P[i * 2 + 1];
  }
}

// acc[dst] += T[src]
__global__ void k_edge(const int* __restrict__ src, const int* __restrict__ dst,
                       const float* __restrict__ T, float* __restrict__ acc, int E) {
  int e = blockIdx.x * 256 + threadIdx.x;
  if (e < E) {
    int s = src[e], d = dst[e];
    float2 t = *(const float2*)&T[s * 2];
    atomicAdd(&acc[d * 2 + 0], t.x);
    atomicAdd(&acc[d * 2 + 1], t.y);
  }
}

// T2 = dis^2 * (T + acc)   ( = S ∘ Â P prepared for second pass )
__global__ void k_mid(const float* __restrict__ dis, const float* __restrict__ T,
                      const float* __restrict__ acc, float* __restrict__ T2, int N) {
  int i = blockIdx.x * 256 + threadIdx.x;
  if (i < N) {
    float d2 = dis[i] * dis[i];
    T2[i * 2 + 0] = d2 * (T[i * 2 + 0] + acc[i * 2 + 0]);
    T2[i * 2 + 1] = d2 * (T[i * 2 + 1] + acc[i * 2 + 1]);
  }
}

// out = (dis*(T2+acc2) + a*u + v) * (Pm + b_out)
__global__ void k_final(const float* __restrict__ dis, const float* __restrict__ T2,
                        const float* __restrict__ acc2, const float* __restrict__ a,
                        const float* __restrict__ uv, const float* __restrict__ Pm,
                        const float* __restrict__ bo, float* __restrict__ out, int N) {
  int i = blockIdx.x * 256 + threadIdx.x;
  if (i < N) {
    float d = dis[i], av = a[i];
    float q0 = d * (T2[i * 2 + 0] + acc2[i * 2 + 0]) + av * uv[0] + uv[2];
    float q1 = d * (T2[i * 2 + 1] + acc2[i * 2 + 1]) + av * uv[1] + uv[3];
    out[i * 2 + 0] = q0 * (Pm[i * 2 + 0] + bo[0]);
    out[i * 2 + 1] = q1 * (Pm[i * 2 + 1] + bo[1]);
  }
}

extern "C" void kernel_launch(void* const* d_in, const int* in_sizes, int n_in,
                              void* d_out, int out_size, void* d_ws, size_t ws_size,
                              hipStream_t stream) {
  const float* mf  = (const float*)d_in[0];
  const float* fe  = (const float*)d_in[1];
  const int*   ei  = (const int*)d_in[2];
  const float* Win = (const float*)d_in[4];
  const float* bin = (const float*)d_in[5];
  const float* Wg1 = (const float*)d_in[6];
  const float* bg1 = (const float*)d_in[7];
  const float* Wg2 = (const float*)d_in[8];
  const float* bg2 = (const float*)d_in[9];
  const float* Wo  = (const float*)d_in[10];
  const float* bo  = (const float*)d_in[11];
  float* out = (float*)d_out;

  const int ED = 128;
  const int N = in_sizes[0] / ED;  // 50000
  const int E = in_sizes[3];       // 800000
  const int* src = ei;
  const int* dst = ei + E;

  char* ws = (char*)d_ws;
  size_t off = 0;
  auto carve = [&](size_t bytes) {
    char* p = ws + off;
    off += (bytes + 255) & ~(size_t)255;
    return p;
  };
  // zero-init region (contiguous): P, Pm, acc1, acc2 [N*2 each], adeg [N]
  float* zbase = (float*)carve((size_t)(N * 2 * 4 + N) * 4);
  float* P    = zbase;
  float* Pm   = zbase + N * 2;
  float* acc1 = zbase + N * 4;
  float* acc2 = zbase + N * 6;
  float* adeg = zbase + N * 8;
  const int ZN = N * 9;
  int*   deg  = (int*)carve((size_t)N * 4);
  float* dis  = (float*)carve((size_t)N * 4);
  float* a    = (float*)carve((size_t)N * 4);
  float* T    = (float*)carve((size_t)N * 2 * 4);
  float* T2   = (float*)carve((size_t)N * 2 * 4);
  float* wb   = (float*)carve((size_t)HD * 2 * 4);
  float* uv   = (float*)carve(4 * 4);
  (void)ws_size; (void)n_in; (void)out_size;

  const int gN = (N + 255) / 256, gE = (E + 255) / 256;

  k_zero<<<(ZN + 255) / 256, 256, 0, stream>>>(zbase, ZN);
  k_deginit<<<gN, 256, 0, stream>>>(deg, N);
  k_deg<<<gE, 256, 0, stream>>>(dst, deg, E);
  k_dis<<<gN, 256, 0, stream>>>(deg, dis, N);
  k_adeg<<<gE, 256, 0, stream>>>(src, dst, dis, adeg, E);
  k_a<<<gN, 256, 0, stream>>>(dis, adeg, a, N);
  k_consts<<<1, 256, 0, stream>>>(Wg1, Wg2, Wo, bg1, bg2, bo, wb, uv);

  dim3 gg((N + 127) / 128, 2);
  k_gemmr<EPI_LRELU><<<gg, 256, 0, stream>>>(mf, nullptr, Win, bin, wb, P, N);
  k_gemmr<EPI_SUB_LRELU><<<gg, 256, 0, stream>>>(fe, mf, Win, bin, Wo, Pm, N);

  k_pre<<<gN, 256, 0, stream>>>(dis, P, T, N);
  k_edge<<<gE, 256, 0, stream>>>(src, dst, T, acc1, E);
  k_mid<<<gN, 256, 0, stream>>>(dis, T, acc1, T2, N);
  k_edge<<<gE, 256, 0, stream>>>(src, dst, T2, acc2, E);
  k_final<<<gN, 256, 0, stream>>>(dis, T2, acc2, a, uv, Pm, bo, out, N);
}

// Round 3
// 225.639 us; speedup vs baseline: 3.0051x; 1.8384x over previous
//
#include <hip/hip_runtime.h>

// GCN forward, algebraically collapsed + CSR-gather aggregation (no fp32 atomics).
//   Z = Â(Â(X1@Wbig) + 1⊗u) + 1⊗v,  Â = D^-1/2 (A+I) D^-1/2
//   X1 = lrelu(MF@W_in+b_in), Wbig = Wg1@Wg2@W_out, u = bg1@Wg2@W_out, v = bg2@W_out+b_out
//   out = Z * (lrelu((F-MF)@W_in+b_in)@W_out + b_out)
// CSR build: slot[e]=atomicAdd(cnt[dst],1) -> scan(cnt)->rp -> csr[rp[d]+slot]=src (no atomics)
// Aggregation: per-node gather over csr on [N,2] data (L2-resident).

#define NEG_SLOPE 0.01f
constexpr int HD = 256;

// ---------------- preprocessing ----------------
__global__ void k_zero(float* __restrict__ p, int n) {
  int i = blockIdx.x * 256 + threadIdx.x;
  if (i < n) p[i] = 0.f;
}

// slot[e] = position of edge e within its dst bucket; cnt[d] = in-degree (no self-loop)
__global__ void k_slot(const int* __restrict__ dst, int* __restrict__ cnt,
                       int* __restrict__ slot, int E) {
  int e = blockIdx.x * 256 + threadIdx.x;
  if (e < E) slot[e] = atomicAdd(&cnt[dst[e]], 1);
}

__global__ void k_dis(const int* __restrict__ cnt, float* __restrict__ dis, int N) {
  int i = blockIdx.x * 256 + threadIdx.x;
  if (i < N) dis[i] = rsqrtf((float)(cnt[i] + 1)); // +1 self-loop
}

// exclusive scan of cnt over N elements, 3-kernel hierarchy
__global__ __launch_bounds__(1024) void k_scan1(const int* __restrict__ cnt,
                                                int* __restrict__ rp,
                                                int* __restrict__ sums, int N) {
  const int i = blockIdx.x * 1024 + threadIdx.x;
  const int lane = threadIdx.x & 63;
  const int wid = threadIdx.x >> 6;
  int v = (i < N) ? cnt[i] : 0;
  int incl = v;
  #pragma unroll
  for (int o = 1; o < 64; o <<= 1) {
    int t = __shfl_up(incl, o, 64);
    if (lane >= o) incl += t;
  }
  __shared__ int ws[16];
  if (lane == 63) ws[wid] = incl;
  __syncthreads();
  if (threadIdx.x == 0) {
    int run = 0;
    #pragma unroll
    for (int w = 0; w < 16; ++w) { int t = ws[w]; ws[w] = run; run += t; }
    sums[blockIdx.x] = run;
  }
  __syncthreads();
  if (i < N) rp[i] = incl - v + ws[wid];
}

__global__ void k_scan2(int* __restrict__ sums, int nb) {
  int lane = threadIdx.x; // blockDim = 64, nb <= 64
  int v = (lane < nb) ? sums[lane] : 0;
  int incl = v;
  #pragma unroll
  for (int o = 1; o < 64; o <<= 1) {
    int t = __shfl_up(incl, o, 64);
    if (lane >= o) incl += t;
  }
  if (lane < nb) sums[lane] = incl - v;
}

__global__ void k_scan3(int* __restrict__ rp, const int* __restrict__ sums, int N, int E) {
  int i = blockIdx.x * 256 + threadIdx.x;
  if (i < N) rp[i] += sums[i >> 10];
  if (i == 0) rp[N] = E;
}

// csr[rp[dst]+slot] = src   (no atomics)
__global__ void k_fill(const int* __restrict__ src, const int* __restrict__ dst,
                       const int* __restrict__ slot, const int* __restrict__ rp,
                       int* __restrict__ csr, int E) {
  int e = blockIdx.x * 256 + threadIdx.x;
  if (e < E) csr[rp[dst[e]] + slot[e]] = src[e];
}

// Wbig = Wg1 @ (Wg2 @ Wo) [256,2]; uv = {u0,u1,v0,v1}
__global__ __launch_bounds__(256) void k_consts(
    const float* __restrict__ Wg1, const float* __restrict__ Wg2,
    const float* __restrict__ Wo, const float* __restrict__ bg1,
    const float* __restrict__ bg2, const float* __restrict__ bo,
    float* __restrict__ wb, float* __restrict__ uv) {
  __shared__ float wt[256][2];
  int r = threadIdx.x;
  float s0 = 0.f, s1 = 0.f;
  for (int k = 0; k < 256; ++k) {
    float w = Wg2[r * 256 + k];
    s0 = fmaf(w, Wo[k * 2 + 0], s0);
    s1 = fmaf(w, Wo[k * 2 + 1], s1);
  }
  wt[r][0] = s0; wt[r][1] = s1;
  __syncthreads();
  float b0 = 0.f, b1 = 0.f;
  for (int k = 0; k < 256; ++k) {
    float w = Wg1[r * 256 + k];
    b0 = fmaf(w, wt[k][0], b0);
    b1 = fmaf(w, wt[k][1], b1);
  }
  wb[r * 2 + 0] = b0; wb[r * 2 + 1] = b1;
  if (r < 2) {
    float u = 0.f, v = 0.f;
    for (int k = 0; k < 256; ++k) {
      u = fmaf(bg1[k], wt[k][r], u);
      v = fmaf(bg2[k], Wo[k * 2 + r], v);
    }
    uv[r] = u;             // u[c]
    uv[2 + r] = v + bo[r]; // v[c]
  }
}

// ---------------- fused GEMM + [256,2] reduction ----------------
// P[row,c] += scale(row) * sum_j lrelu(A[row,:]@W[:,col_j] + bias[col_j]) * wr[col_j,c]
enum { EPI_MAIN = 0, EPI_MASK = 1 }; // MAIN: lrelu+dis-scale; MASK: (A-A2)+lrelu, no scale

template <int EPI>
__global__ __launch_bounds__(256) void k_gemmr(
    const float* __restrict__ A, const float* __restrict__ A2,
    const float* __restrict__ W, const float* __restrict__ bias,
    const float* __restrict__ wr, const float* __restrict__ scale,
    float* __restrict__ P, int M) {
  constexpr int K = 128, BM = 128, BN = 128, BK = 16;
  __shared__ float As[BK][BM + 4];
  __shared__ float Bs[BK][BN + 4];
  const int tid = threadIdx.x;
  const int tx = tid & 15, ty = tid >> 4;
  const int bm = blockIdx.x * BM, bn = blockIdx.y * BN;
  const int m0 = ty * 8, n0 = tx * 8;

  float acc[8][8];
  #pragma unroll
  for (int i = 0; i < 8; ++i)
    #pragma unroll
    for (int j = 0; j < 8; ++j) acc[i][j] = 0.f;

  for (int kt = 0; kt < K; kt += BK) {
    #pragma unroll
    for (int p = 0; p < 2; ++p) {
      int idx = tid + p * 256;
      int ar = idx >> 2;
      int ac = (idx & 3) * 4;
      int gr = bm + ar;
      if (gr >= M) gr = M - 1;
      float4 v = *(const float4*)&A[(size_t)gr * K + kt + ac];
      if constexpr (EPI == EPI_MASK) {
        float4 v2 = *(const float4*)&A2[(size_t)gr * K + kt + ac];
        v.x -= v2.x; v.y -= v2.y; v.z -= v2.z; v.w -= v2.w;
      }
      As[ac + 0][ar] = v.x;
      As[ac + 1][ar] = v.y;
      As[ac + 2][ar] = v.z;
      As[ac + 3][ar] = v.w;
    }
    #pragma unroll
    for (int p = 0; p < 2; ++p) {
      int idx = tid + p * 256;
      int br = idx >> 5;
      int bc = (idx & 31) * 4;
      *(float4*)&Bs[br][bc] = *(const float4*)&W[(size_t)(kt + br) * HD + bn + bc];
    }
    __syncthreads();
    #pragma unroll
    for (int k = 0; k < BK; ++k) {
      float4 A0 = *(const float4*)&As[k][m0];
      float4 A1 = *(const float4*)&As[k][m0 + 4];
      float4 B0 = *(const float4*)&Bs[k][n0];
      float4 B1 = *(const float4*)&Bs[k][n0 + 4];
      float aa[8] = {A0.x, A0.y, A0.z, A0.w, A1.x, A1.y, A1.z, A1.w};
      float bb[8] = {B0.x, B0.y, B0.z, B0.w, B1.x, B1.y, B1.z, B1.w};
      #pragma unroll
      for (int i = 0; i < 8; ++i)
        #pragma unroll
        for (int j = 0; j < 8; ++j) acc[i][j] = fmaf(aa[i], bb[j], acc[i][j]);
    }
    __syncthreads();
  }

  float w0[8], w1[8], bb[8];
  #pragma unroll
  for (int j = 0; j < 8; ++j) {
    int col = bn + n0 + j;
    w0[j] = wr[col * 2 + 0];
    w1[j] = wr[col * 2 + 1];
    bb[j] = bias[col];
  }
  float p0[8], p1[8];
  #pragma unroll
  for (int i = 0; i < 8; ++i) {
    float s0 = 0.f, s1 = 0.f;
    #pragma unroll
    for (int j = 0; j < 8; ++j) {
      float t = acc[i][j] + bb[j];
      t = t > 0.f ? t : NEG_SLOPE * t;
      s0 = fmaf(t, w0[j], s0);
      s1 = fmaf(t, w1[j], s1);
    }
    p0[i] = s0; p1[i] = s1;
  }
  #pragma unroll
  for (int o = 1; o < 16; o <<= 1) {
    #pragma unroll
    for (int i = 0; i < 8; ++i) {
      p0[i] += __shfl_xor(p0[i], o, 16);
      p1[i] += __shfl_xor(p1[i], o, 16);
    }
  }
  if (tx == 0) {
    #pragma unroll
    for (int i = 0; i < 8; ++i) {
      int row = bm + m0 + i;
      if (row < M) {
        float s = 1.f;
        if constexpr (EPI == EPI_MAIN) s = scale[row];
        atomicAdd(&P[row * 2 + 0], s * p0[i]);
        atomicAdd(&P[row * 2 + 1], s * p1[i]);
      }
    }
  }
}

// ---------------- gather passes (4 lanes per node) ----------------
// pass1: T2[n] = dis[n]*(dis[n]*(T[n]+sum_nbr T[s]) + u)
__global__ __launch_bounds__(256) void k_gather1(
    const int* __restrict__ rp, const int* __restrict__ csr,
    const float* __restrict__ T, const float* __restrict__ dis,
    const float* __restrict__ uv, float* __restrict__ T2, int N) {
  int t = threadIdx.x;
  int n = blockIdx.x * 64 + (t >> 2);
  int l = t & 3;
  if (n >= N) return;
  int s0 = rp[n], s1 = rp[n + 1];
  float a0 = 0.f, a1 = 0.f;
  for (int j = s0 + l; j < s1; j += 4) {
    int s = csr[j];
    float2 v = *(const float2*)&T[s * 2];
    a0 += v.x; a1 += v.y;
  }
  a0 += __shfl_xor(a0, 1, 4); a1 += __shfl_xor(a1, 1, 4);
  a0 += __shfl_xor(a0, 2, 4); a1 += __shfl_xor(a1, 2, 4);
  if (l == 0) {
    float d = dis[n];
    float2 tv = *(const float2*)&T[n * 2];
    float h0 = d * (tv.x + a0) + uv[0];
    float h1 = d * (tv.y + a1) + uv[1];
    T2[n * 2 + 0] = d * h0;
    T2[n * 2 + 1] = d * h1;
  }
}

// pass2 fused with final: out[n] = (dis[n]*(T2[n]+sum T2[s]) + v) * (Pm[n] + bo)
__global__ __launch_bounds__(256) void k_gather2(
    const int* __restrict__ rp, const int* __restrict__ csr,
    const float* __restrict__ T2, const float* __restrict__ dis,
    const float* __restrict__ uv, const float* __restrict__ Pm,
    const float* __restrict__ bo, float* __restrict__ out, int N) {
  int t = threadIdx.x;
  int n = blockIdx.x * 64 + (t >> 2);
  int l = t & 3;
  if (n >= N) return;
  int s0 = rp[n], s1 = rp[n + 1];
  float a0 = 0.f, a1 = 0.f;
  for (int j = s0 + l; j < s1; j += 4) {
    int s = csr[j];
    float2 v = *(const float2*)&T2[s * 2];
    a0 += v.x; a1 += v.y;
  }
  a0 += __shfl_xor(a0, 1, 4); a1 += __shfl_xor(a1, 1, 4);
  a0 += __shfl_xor(a0, 2, 4); a1 += __shfl_xor(a1, 2, 4);
  if (l == 0) {
    float d = dis[n];
    float2 tv = *(const float2*)&T2[n * 2];
    float z0 = d * (tv.x + a0) + uv[2];
    float z1 = d * (tv.y + a1) + uv[3];
    out[n * 2 + 0] = z0 * (Pm[n * 2 + 0] + bo[0]);
    out[n * 2 + 1] = z1 * (Pm[n * 2 + 1] + bo[1]);
  }
}

extern "C" void kernel_launch(void* const* d_in, const int* in_sizes, int n_in,
                              void* d_out, int out_size, void* d_ws, size_t ws_size,
                              hipStream_t stream) {
  const float* mf  = (const float*)d_in[0];
  const float* fe  = (const float*)d_in[1];
  const int*   ei  = (const int*)d_in[2];
  const float* Win = (const float*)d_in[4];
  const float* bin = (const float*)d_in[5];
  const float* Wg1 = (const float*)d_in[6];
  const float* bg1 = (const float*)d_in[7];
  const float* Wg2 = (const float*)d_in[8];
  const float* bg2 = (const float*)d_in[9];
  const float* Wo  = (const float*)d_in[10];
  const float* bo  = (const float*)d_in[11];
  float* out = (float*)d_out;

  const int ED = 128;
  const int N = in_sizes[0] / ED;  // 50000
  const int E = in_sizes[3];       // 800000
  const int* src = ei;
  const int* dst = ei + E;

  char* ws = (char*)d_ws;
  size_t off = 0;
  auto carve = [&](size_t bytes) {
    char* p = ws + off;
    off += (bytes + 255) & ~(size_t)255;
    return p;
  };
  // zero-init region: T [N*2], Pm [N*2], cnt [N]
  float* zbase = (float*)carve((size_t)N * 5 * 4);
  float* T   = zbase;
  float* Pm  = zbase + N * 2;
  int*   cnt = (int*)(zbase + N * 4);
  const int ZN = N * 5;
  float* dis  = (float*)carve((size_t)N * 4);
  int*   rp   = (int*)carve((size_t)(N + 1) * 4);
  int*   slot = (int*)carve((size_t)E * 4);
  int*   csr  = (int*)carve((size_t)E * 4);
  int*   sums = (int*)carve(64 * 4);
  float* T2   = (float*)carve((size_t)N * 2 * 4);
  float* wb   = (float*)carve((size_t)HD * 2 * 4);
  float* uv   = (float*)carve(4 * 4);
  (void)ws_size; (void)n_in; (void)out_size;

  const int gN = (N + 255) / 256, gE = (E + 255) / 256;
  const int nb = (N + 1023) / 1024; // 49 <= 64

  k_zero<<<(ZN + 255) / 256, 256, 0, stream>>>(zbase, ZN);
  k_slot<<<gE, 256, 0, stream>>>(dst, cnt, slot, E);
  k_dis<<<gN, 256, 0, stream>>>(cnt, dis, N);
  k_scan1<<<nb, 1024, 0, stream>>>(cnt, rp, sums, N);
  k_scan2<<<1, 64, 0, stream>>>(sums, nb);
  k_scan3<<<gN, 256, 0, stream>>>(rp, sums, N, E);
  k_fill<<<gE, 256, 0, stream>>>(src, dst, slot, rp, csr, E);
  k_consts<<<1, 256, 0, stream>>>(Wg1, Wg2, Wo, bg1, bg2, bo, wb, uv);

  dim3 gg((N + 127) / 128, 2);
  k_gemmr<EPI_MAIN><<<gg, 256, 0, stream>>>(mf, nullptr, Win, bin, wb, dis, T, N);
  k_gemmr<EPI_MASK><<<gg, 256, 0, stream>>>(fe, mf, Win, bin, Wo, nullptr, Pm, N);

  const int gG = (N + 63) / 64;
  k_gather1<<<gG, 256, 0, stream>>>(rp, csr, T, dis, uv, T2, N);
  k_gather2<<<gG, 256, 0, stream>>>(rp, csr, T2, dis, uv, Pm, bo, out, N);
}

// Round 4
// 161.210 us; speedup vs baseline: 4.2061x; 1.3997x over previous
//
#include <hip/hip_runtime.h>

// GCN forward, algebraically collapsed + CSR-gather aggregation + split-bf16 MFMA GEMMs.
//   Z = Â(Â(X1@Wbig) + 1⊗u) + 1⊗v,  Â = D^-1/2 (A+I) D^-1/2
//   X1 = lrelu(MF@W_in+b_in), Wbig = Wg1@Wg2@W_out, u = bg1@Wg2@W_out, v = bg2@W_out+b_out
//   out = Z * (lrelu((F-MF)@W_in+b_in)@W_out + b_out)
// GEMM: fp32 A split into bf16 hi+lo, 3x mfma_f32_16x16x32_bf16 products, fp32 acc.
// W pre-split into MFMA-fragment-ordered hi/lo bf16 (one dwordx4 per fragment per lane).

#define NEG_SLOPE 0.01f
constexpr int HD = 256;

typedef __bf16 bf16x8 __attribute__((ext_vector_type(8)));
typedef unsigned short u16x8 __attribute__((ext_vector_type(8)));
typedef float f32x4 __attribute__((ext_vector_type(4)));

// split fp32 -> bf16 hi (truncate) + bf16 lo (RNE of remainder)
__device__ inline void split1(float v, unsigned short& h, unsigned short& l) {
  unsigned u = __float_as_uint(v);
  unsigned hb = u & 0xFFFF0000u;
  float lf = v - __uint_as_float(hb);
  unsigned ul = __float_as_uint(lf);
  h = (unsigned short)(hb >> 16);
  l = (unsigned short)((ul + 0x7FFFu + ((ul >> 16) & 1u)) >> 16);
}

// ---------------- preprocessing ----------------
// slot[e] = position of edge e within its dst bucket; cnt[d] = in-degree (no self-loop)
__global__ void k_slot(const int* __restrict__ dst, int* __restrict__ cnt,
                       int* __restrict__ slot, int E) {
  int e = blockIdx.x * 256 + threadIdx.x;
  if (e < E) slot[e] = atomicAdd(&cnt[dst[e]], 1);
}

// exclusive scan of cnt (3-kernel hierarchy); also dis = rsqrt(cnt+1)
__global__ __launch_bounds__(1024) void k_scan1(const int* __restrict__ cnt,
                                                int* __restrict__ rp,
                                                int* __restrict__ sums,
                                                float* __restrict__ dis, int N) {
  const int i = blockIdx.x * 1024 + threadIdx.x;
  const int lane = threadIdx.x & 63;
  const int wid = threadIdx.x >> 6;
  int v = (i < N) ? cnt[i] : 0;
  if (i < N) dis[i] = rsqrtf((float)(v + 1));
  int incl = v;
  #pragma unroll
  for (int o = 1; o < 64; o <<= 1) {
    int t = __shfl_up(incl, o, 64);
    if (lane >= o) incl += t;
  }
  __shared__ int ws[16];
  if (lane == 63) ws[wid] = incl;
  __syncthreads();
  if (threadIdx.x == 0) {
    int run = 0;
    #pragma unroll
    for (int w = 0; w < 16; ++w) { int t = ws[w]; ws[w] = run; run += t; }
    sums[blockIdx.x] = run;
  }
  __syncthreads();
  if (i < N) rp[i] = incl - v + ws[wid];
}

__global__ void k_scan2(int* __restrict__ sums, int nb) {
  int lane = threadIdx.x; // blockDim = 64, nb <= 64
  int v = (lane < nb) ? sums[lane] : 0;
  int incl = v;
  #pragma unroll
  for (int o = 1; o < 64; o <<= 1) {
    int t = __shfl_up(incl, o, 64);
    if (lane >= o) incl += t;
  }
  if (lane < nb) sums[lane] = incl - v;
}

__global__ void k_scan3(int* __restrict__ rp, const int* __restrict__ sums, int N, int E) {
  int i = blockIdx.x * 256 + threadIdx.x;
  if (i < N) rp[i] += sums[i >> 10];
  if (i == 0) rp[N] = E;
}

// csr[rp[dst]+slot] = src   (no atomics)
__global__ void k_fill(const int* __restrict__ src, const int* __restrict__ dst,
                       const int* __restrict__ slot, const int* __restrict__ rp,
                       int* __restrict__ csr, int E) {
  int e = blockIdx.x * 256 + threadIdx.x;
  if (e < E) csr[rp[dst[e]] + slot[e]] = src[e];
}

// W [128][256] fp32 -> fragment-ordered hi/lo bf16.
// frag f: ntile = f>>3, kstep = (f>>1)&3, hl = f&1. Lane's 8 elems:
//   B[kstep*32 + (lane>>4)*8 + j][ntile*16 + (lane&15)]
__global__ void k_wsplit(const float* __restrict__ W, u16x8* __restrict__ Wf) {
  int f = blockIdx.x;       // 0..127
  int lane = threadIdx.x;   // 0..63
  int nt = f >> 3, ks = (f >> 1) & 3, hl = f & 1;
  int n = nt * 16 + (lane & 15);
  int k0 = ks * 32 + (lane >> 4) * 8;
  u16x8 outv;
  #pragma unroll
  for (int j = 0; j < 8; ++j) {
    unsigned short h, l;
    split1(W[(size_t)(k0 + j) * HD + n], h, l);
    outv[j] = hl ? l : h;
  }
  Wf[f * 64 + lane] = outv;
}

// Wbig = Wg1 @ (Wg2 @ Wo) [256,2]; uv = {u0,u1,v0,v1}
__global__ __launch_bounds__(256) void k_consts(
    const float* __restrict__ Wg1, const float* __restrict__ Wg2,
    const float* __restrict__ Wo, const float* __restrict__ bg1,
    const float* __restrict__ bg2, const float* __restrict__ bo,
    float* __restrict__ wb, float* __restrict__ uv) {
  __shared__ float wt[256][2];
  int r = threadIdx.x;
  float s0 = 0.f, s1 = 0.f;
  for (int k = 0; k < 256; ++k) {
    float w = Wg2[r * 256 + k];
    s0 = fmaf(w, Wo[k * 2 + 0], s0);
    s1 = fmaf(w, Wo[k * 2 + 1], s1);
  }
  wt[r][0] = s0; wt[r][1] = s1;
  __syncthreads();
  float b0 = 0.f, b1 = 0.f;
  for (int k = 0; k < 256; ++k) {
    float w = Wg1[r * 256 + k];
    b0 = fmaf(w, wt[k][0], b0);
    b1 = fmaf(w, wt[k][1], b1);
  }
  wb[r * 2 + 0] = b0; wb[r * 2 + 1] = b1;
  if (r < 2) {
    float u = 0.f, v = 0.f;
    for (int k = 0; k < 256; ++k) {
      u = fmaf(bg1[k], wt[k][r], u);
      v = fmaf(bg2[k], Wo[k * 2 + r], v);
    }
    uv[r] = u;             // u[c]
    uv[2 + r] = v + bo[r]; // v[c]
  }
}

// ---------------- MFMA GEMM + fused [256,2] reduction ----------------
// P[row,c] = scale(row) * sum_col lrelu(A[row,:]@W[:,col] + bias[col]) * wr[col,c]
// One wave per 16-row strip, full 256 cols. No LDS.
enum { EPI_MAIN = 0, EPI_MASK = 1 };

template <int EPI>
__global__ __launch_bounds__(256) void k_gemmr(
    const float* __restrict__ A, const float* __restrict__ A2,
    const u16x8* __restrict__ Wf, const float* __restrict__ bias,
    const float* __restrict__ wr, const float* __restrict__ scale,
    float* __restrict__ P, int M) {
  const int tid = threadIdx.x;
  const int lane = tid & 63, wid = tid >> 6;
  const int base = blockIdx.x * 64 + wid * 16;
  int arow = base + (lane & 15);
  if (arow >= M) arow = M - 1;
  const int kb = (lane >> 4) * 8;
  const float* ap = A + (size_t)arow * 128 + kb;

  // A panel -> registers, split hi/lo
  bf16x8 ahi[4], alo[4];
  #pragma unroll
  for (int ks = 0; ks < 4; ++ks) {
    float x[8];
    *(float4*)&x[0] = *(const float4*)(ap + ks * 32);
    *(float4*)&x[4] = *(const float4*)(ap + ks * 32 + 4);
    if constexpr (EPI == EPI_MASK) {
      const float* ap2 = A2 + (size_t)arow * 128 + kb;
      float y[8];
      *(float4*)&y[0] = *(const float4*)(ap2 + ks * 32);
      *(float4*)&y[4] = *(const float4*)(ap2 + ks * 32 + 4);
      #pragma unroll
      for (int j = 0; j < 8; ++j) x[j] -= y[j];
    }
    u16x8 h, l;
    #pragma unroll
    for (int j = 0; j < 8; ++j) {
      unsigned short hh, ll;
      split1(x[j], hh, ll);
      h[j] = hh; l[j] = ll;
    }
    ahi[ks] = __builtin_bit_cast(bf16x8, h);
    alo[ks] = __builtin_bit_cast(bf16x8, l);
  }

  float s0[4] = {0.f, 0.f, 0.f, 0.f}, s1[4] = {0.f, 0.f, 0.f, 0.f};
  #pragma unroll
  for (int nt = 0; nt < 16; ++nt) {
    f32x4 acc = {0.f, 0.f, 0.f, 0.f};
    #pragma unroll
    for (int ks = 0; ks < 4; ++ks) {
      bf16x8 bh = __builtin_bit_cast(bf16x8, Wf[((nt * 4 + ks) * 2 + 0) * 64 + lane]);
      bf16x8 bl = __builtin_bit_cast(bf16x8, Wf[((nt * 4 + ks) * 2 + 1) * 64 + lane]);
      acc = __builtin_amdgcn_mfma_f32_16x16x32_bf16(ahi[ks], bh, acc, 0, 0, 0);
      acc = __builtin_amdgcn_mfma_f32_16x16x32_bf16(alo[ks], bh, acc, 0, 0, 0);
      acc = __builtin_amdgcn_mfma_f32_16x16x32_bf16(ahi[ks], bl, acc, 0, 0, 0);
    }
    // epilogue for this n-tile: D col = lane&15, row = (lane>>4)*4 + r
    const int col = nt * 16 + (lane & 15);
    const float bcol = bias[col];
    const float w0 = wr[col * 2 + 0], w1 = wr[col * 2 + 1];
    #pragma unroll
    for (int r = 0; r < 4; ++r) {
      float t = acc[r] + bcol;
      t = t > 0.f ? t : NEG_SLOPE * t;
      s0[r] = fmaf(t, w0, s0[r]);
      s1[r] = fmaf(t, w1, s1[r]);
    }
  }
  // reduce across the 16 lanes of each (lane>>4) group (cols 0..255 covered)
  #pragma unroll
  for (int o = 1; o < 16; o <<= 1) {
    #pragma unroll
    for (int r = 0; r < 4; ++r) {
      s0[r] += __shfl_xor(s0[r], o, 16);
      s1[r] += __shfl_xor(s1[r], o, 16);
    }
  }
  if ((lane & 15) == 0) {
    #pragma unroll
    for (int r = 0; r < 4; ++r) {
      int row = base + (lane >> 4) * 4 + r;
      if (row < M) {
        float s = 1.f;
        if constexpr (EPI == EPI_MAIN) s = scale[row];
        P[row * 2 + 0] = s * s0[r];
        P[row * 2 + 1] = s * s1[r];
      }
    }
  }
}

// ---------------- gather passes (4 lanes per node) ----------------
// pass1: T2[n] = dis[n]*(dis[n]*(T[n]+sum_nbr T[s]) + u)
__global__ __launch_bounds__(256) void k_gather1(
    const int* __restrict__ rp, const int* __restrict__ csr,
    const float* __restrict__ T, const float* __restrict__ dis,
    const float* __restrict__ uv, float* __restrict__ T2, int N) {
  int t = threadIdx.x;
  int n = blockIdx.x * 64 + (t >> 2);
  int l = t & 3;
  if (n >= N) return;
  int s0 = rp[n], s1 = rp[n + 1];
  float a0 = 0.f, a1 = 0.f;
  for (int j = s0 + l; j < s1; j += 4) {
    int s = csr[j];
    float2 v = *(const float2*)&T[s * 2];
    a0 += v.x; a1 += v.y;
  }
  a0 += __shfl_xor(a0, 1, 4); a1 += __shfl_xor(a1, 1, 4);
  a0 += __shfl_xor(a0, 2, 4); a1 += __shfl_xor(a1, 2, 4);
  if (l == 0) {
    float d = dis[n];
    float2 tv = *(const float2*)&T[n * 2];
    T2[n * 2 + 0] = d * (d * (tv.x + a0) + uv[0]);
    T2[n * 2 + 1] = d * (d * (tv.y + a1) + uv[1]);
  }
}

// pass2 fused final: out[n] = (dis[n]*(T2[n]+sum T2[s]) + v) * (Pm[n] + bo)
__global__ __launch_bounds__(256) void k_gather2(
    const int* __restrict__ rp, const int* __restrict__ csr,
    const float* __restrict__ T2, const float* __restrict__ dis,
    const float* __restrict__ uv, const float* __restrict__ Pm,
    const float* __restrict__ bo, float* __restrict__ out, int N) {
  int t = threadIdx.x;
  int n = blockIdx.x * 64 + (t >> 2);
  int l = t & 3;
  if (n >= N) return;
  int s0 = rp[n], s1 = rp[n + 1];
  float a0 = 0.f, a1 = 0.f;
  for (int j = s0 + l; j < s1; j += 4) {
    int s = csr[j];
    float2 v = *(const float2*)&T2[s * 2];
    a0 += v.x; a1 += v.y;
  }
  a0 += __shfl_xor(a0, 1, 4); a1 += __shfl_xor(a1, 1, 4);
  a0 += __shfl_xor(a0, 2, 4); a1 += __shfl_xor(a1, 2, 4);
  if (l == 0) {
    float d = dis[n];
    float2 tv = *(const float2*)&T2[n * 2];
    float z0 = d * (tv.x + a0) + uv[2];
    float z1 = d * (tv.y + a1) + uv[3];
    out[n * 2 + 0] = z0 * (Pm[n * 2 + 0] + bo[0]);
    out[n * 2 + 1] = z1 * (Pm[n * 2 + 1] + bo[1]);
  }
}

extern "C" void kernel_launch(void* const* d_in, const int* in_sizes, int n_in,
                              void* d_out, int out_size, void* d_ws, size_t ws_size,
                              hipStream_t stream) {
  const float* mf  = (const float*)d_in[0];
  const float* fe  = (const float*)d_in[1];
  const int*   ei  = (const int*)d_in[2];
  const float* Win = (const float*)d_in[4];
  const float* bin = (const float*)d_in[5];
  const float* Wg1 = (const float*)d_in[6];
  const float* bg1 = (const float*)d_in[7];
  const float* Wg2 = (const float*)d_in[8];
  const float* bg2 = (const float*)d_in[9];
  const float* Wo  = (const float*)d_in[10];
  const float* bo  = (const float*)d_in[11];
  float* out = (float*)d_out;

  const int ED = 128;
  const int N = in_sizes[0] / ED;  // 50000
  const int E = in_sizes[3];       // 800000
  const int* src = ei;
  const int* dst = ei + E;

  char* ws = (char*)d_ws;
  size_t off = 0;
  auto carve = [&](size_t bytes) {
    char* p = ws + off;
    off += (bytes + 255) & ~(size_t)255;
    return p;
  };
  int*   cnt  = (int*)carve((size_t)N * 4);
  float* dis  = (float*)carve((size_t)N * 4);
  int*   rp   = (int*)carve((size_t)(N + 1) * 4);
  int*   slot = (int*)carve((size_t)E * 4);
  int*   csr  = (int*)carve((size_t)E * 4);
  int*   sums = (int*)carve(64 * 4);
  float* T    = (float*)carve((size_t)N * 2 * 4);
  float* T2   = (float*)carve((size_t)N * 2 * 4);
  float* Pm   = (float*)carve((size_t)N * 2 * 4);
  float* wb   = (float*)carve((size_t)HD * 2 * 4);
  float* uv   = (float*)carve(4 * 4);
  u16x8* Wf   = (u16x8*)carve((size_t)128 * 64 * 16); // 128 KB
  (void)ws_size; (void)n_in; (void)out_size;

  const int gN = (N + 255) / 256, gE = (E + 255) / 256;
  const int nb = (N + 1023) / 1024; // 49 <= 64

  hipMemsetAsync(cnt, 0, (size_t)N * 4, stream);
  k_slot<<<gE, 256, 0, stream>>>(dst, cnt, slot, E);
  k_scan1<<<nb, 1024, 0, stream>>>(cnt, rp, sums, dis, N);
  k_scan2<<<1, 64, 0, stream>>>(sums, nb);
  k_scan3<<<gN, 256, 0, stream>>>(rp, sums, N, E);
  k_fill<<<gE, 256, 0, stream>>>(src, dst, slot, rp, csr, E);
  k_wsplit<<<128, 64, 0, stream>>>(Win, Wf);
  k_consts<<<1, 256, 0, stream>>>(Wg1, Wg2, Wo, bg1, bg2, bo, wb, uv);

  const int gM = (N + 63) / 64; // 64 rows per block (4 waves x 16)
  k_gemmr<EPI_MAIN><<<gM, 256, 0, stream>>>(mf, mf, Wf, bin, wb, dis, T, N);
  k_gemmr<EPI_MASK><<<gM, 256, 0, stream>>>(fe, mf, Wf, bin, Wo, nullptr, Pm, N);

  const int gG = (N + 63) / 64;
  k_gather1<<<gG, 256, 0, stream>>>(rp, csr, T, dis, uv, T2, N);
  k_gather2<<<gG, 256, 0, stream>>>(rp, csr, T2, dis, uv, Pm, bo, out, N);
}

// Round 5
// 154.528 us; speedup vs baseline: 4.3880x; 1.0432x over previous
//
#include <hip/hip_runtime.h>

// GCN forward, algebraically collapsed + CSR-gather aggregation + split-bf16 MFMA GEMMs.
//   Z = Â(Â(X1@Wbig) + 1⊗u) + 1⊗v,  Â = D^-1/2 (A+I) D^-1/2
//   X1 = lrelu(MF@W_in+b_in), Wbig = Wg1@Wg2@W_out, u = bg1@Wg2@W_out, v = bg2@W_out+b_out
//   out = Z * (lrelu((F-MF)@W_in+b_in)@W_out + b_out)
// R4: custom prep kernel (no hipMemsetAsync), CSR slot-atomics fused into the GEMM
// launch (atomic LLC traffic hides under MFMA compute). dis-scale moved into gather1
// (dis depends on cnt, which is only final after the fused kernel). 8 launches.

#define NEG_SLOPE 0.01f
constexpr int HD = 256;

typedef __bf16 bf16x8 __attribute__((ext_vector_type(8)));
typedef unsigned short u16x8 __attribute__((ext_vector_type(8)));
typedef float f32x4 __attribute__((ext_vector_type(4)));

__device__ inline void split1(float v, unsigned short& h, unsigned short& l) {
  unsigned u = __float_as_uint(v);
  unsigned hb = u & 0xFFFF0000u;
  float lf = v - __uint_as_float(hb);
  unsigned ul = __float_as_uint(lf);
  h = (unsigned short)(hb >> 16);
  l = (unsigned short)((ul + 0x7FFFu + ((ul >> 16) & 1u)) >> 16);
}

// ---------------- prep: W-split + consts + zero(cnt), one launch ----------------
__global__ __launch_bounds__(256) void k_prep(
    const float* __restrict__ Win, u16x8* __restrict__ Wf,
    const float* __restrict__ Wg1, const float* __restrict__ Wg2,
    const float* __restrict__ Wo, const float* __restrict__ bg1,
    const float* __restrict__ bg2, const float* __restrict__ bo,
    float* __restrict__ wb, float* __restrict__ uv,
    int* __restrict__ cnt, int N) {
  __shared__ float wt[256][2];
  const int bid = blockIdx.x, tid = threadIdx.x;
  if (bid < 32) {
    int f = bid * 4 + (tid >> 6);
    int lane = tid & 63;
    int nt = f >> 3, ks = (f >> 1) & 3, hl = f & 1;
    int n = nt * 16 + (lane & 15);
    int k0 = ks * 32 + (lane >> 4) * 8;
    u16x8 outv;
    #pragma unroll
    for (int j = 0; j < 8; ++j) {
      unsigned short h, l;
      split1(Win[(size_t)(k0 + j) * HD + n], h, l);
      outv[j] = hl ? l : h;
    }
    Wf[f * 64 + lane] = outv;
  } else if (bid == 32) {
    int r = tid;
    float s0 = 0.f, s1 = 0.f;
    for (int k = 0; k < 256; ++k) {
      float w = Wg2[r * 256 + k];
      s0 = fmaf(w, Wo[k * 2 + 0], s0);
      s1 = fmaf(w, Wo[k * 2 + 1], s1);
    }
    wt[r][0] = s0; wt[r][1] = s1;
    __syncthreads();
    float b0 = 0.f, b1 = 0.f;
    for (int k = 0; k < 256; ++k) {
      float w = Wg1[r * 256 + k];
      b0 = fmaf(w, wt[k][0], b0);
      b1 = fmaf(w, wt[k][1], b1);
    }
    wb[r * 2 + 0] = b0; wb[r * 2 + 1] = b1;
    if (r < 2) {
      float u = 0.f, v = 0.f;
      for (int k = 0; k < 256; ++k) {
        u = fmaf(bg1[k], wt[k][r], u);
        v = fmaf(bg2[k], Wo[k * 2 + r], v);
      }
      uv[r] = u;
      uv[2 + r] = v + bo[r];
    }
  } else {
    int i = (bid - 33) * 256 + tid;
    if (i < N) cnt[i] = 0;
  }
}

// ---------------- scans ----------------
__global__ __launch_bounds__(1024) void k_scan1(const int* __restrict__ cnt,
                                                int* __restrict__ rp,
                                                int* __restrict__ sums,
                                                float* __restrict__ dis, int N) {
  const int i = blockIdx.x * 1024 + threadIdx.x;
  const int lane = threadIdx.x & 63;
  const int wid = threadIdx.x >> 6;
  int v = (i < N) ? cnt[i] : 0;
  if (i < N) dis[i] = rsqrtf((float)(v + 1));
  int incl = v;
  #pragma unroll
  for (int o = 1; o < 64; o <<= 1) {
    int t = __shfl_up(incl, o, 64);
    if (lane >= o) incl += t;
  }
  __shared__ int ws[16];
  if (lane == 63) ws[wid] = incl;
  __syncthreads();
  if (threadIdx.x == 0) {
    int run = 0;
    #pragma unroll
    for (int w = 0; w < 16; ++w) { int t = ws[w]; ws[w] = run; run += t; }
    sums[blockIdx.x] = run;
  }
  __syncthreads();
  if (i < N) rp[i] = incl - v + ws[wid];
}

__global__ void k_scan2(int* __restrict__ sums, int nb) {
  int lane = threadIdx.x;
  int v = (lane < nb) ? sums[lane] : 0;
  int incl = v;
  #pragma unroll
  for (int o = 1; o < 64; o <<= 1) {
    int t = __shfl_up(incl, o, 64);
    if (lane >= o) incl += t;
  }
  if (lane < nb) sums[lane] = incl - v;
}

__global__ void k_scan3(int* __restrict__ rp, const int* __restrict__ sums, int N, int E) {
  int i = blockIdx.x * 256 + threadIdx.x;
  if (i < N) rp[i] += sums[i >> 10];
  if (i == 0) rp[N] = E;
}

__global__ void k_fill(const int* __restrict__ src, const int* __restrict__ dst,
                       const int* __restrict__ slot, const int* __restrict__ rp,
                       int* __restrict__ csr, int E) {
  int e = blockIdx.x * 256 + threadIdx.x;
  if (e < E) csr[rp[dst[e]] + slot[e]] = src[e];
}

// ---------------- fused: slot atomics + MFMA GEMM + [256,2] reduction ----------------
template <bool MASK>
__device__ __forceinline__ void gemm_body(
    const float* __restrict__ A, const float* __restrict__ A2,
    const u16x8* __restrict__ Wf, const float* __restrict__ bias,
    const float* __restrict__ wr, float* __restrict__ P, int M, int gbid) {
  const int tid = threadIdx.x;
  const int lane = tid & 63, wid = tid >> 6;
  const int base = gbid * 64 + wid * 16;
  int arow = base + (lane & 15);
  if (arow >= M) arow = M - 1;
  const int kb = (lane >> 4) * 8;
  const float* ap = A + (size_t)arow * 128 + kb;

  bf16x8 ahi[4], alo[4];
  #pragma unroll
  for (int ks = 0; ks < 4; ++ks) {
    float x[8];
    *(float4*)&x[0] = *(const float4*)(ap + ks * 32);
    *(float4*)&x[4] = *(const float4*)(ap + ks * 32 + 4);
    if constexpr (MASK) {
      const float* ap2 = A2 + (size_t)arow * 128 + kb;
      float y[8];
      *(float4*)&y[0] = *(const float4*)(ap2 + ks * 32);
      *(float4*)&y[4] = *(const float4*)(ap2 + ks * 32 + 4);
      #pragma unroll
      for (int j = 0; j < 8; ++j) x[j] -= y[j];
    }
    u16x8 h, l;
    #pragma unroll
    for (int j = 0; j < 8; ++j) {
      unsigned short hh, ll;
      split1(x[j], hh, ll);
      h[j] = hh; l[j] = ll;
    }
    ahi[ks] = __builtin_bit_cast(bf16x8, h);
    alo[ks] = __builtin_bit_cast(bf16x8, l);
  }

  float s0[4] = {0.f, 0.f, 0.f, 0.f}, s1[4] = {0.f, 0.f, 0.f, 0.f};
  #pragma unroll
  for (int nt = 0; nt < 16; ++nt) {
    f32x4 acc = {0.f, 0.f, 0.f, 0.f};
    #pragma unroll
    for (int ks = 0; ks < 4; ++ks) {
      bf16x8 bh = __builtin_bit_cast(bf16x8, Wf[((nt * 4 + ks) * 2 + 0) * 64 + lane]);
      bf16x8 bl = __builtin_bit_cast(bf16x8, Wf[((nt * 4 + ks) * 2 + 1) * 64 + lane]);
      acc = __builtin_amdgcn_mfma_f32_16x16x32_bf16(ahi[ks], bh, acc, 0, 0, 0);
      acc = __builtin_amdgcn_mfma_f32_16x16x32_bf16(alo[ks], bh, acc, 0, 0, 0);
      acc = __builtin_amdgcn_mfma_f32_16x16x32_bf16(ahi[ks], bl, acc, 0, 0, 0);
    }
    const int col = nt * 16 + (lane & 15);
    const float bcol = bias[col];
    const float w0 = wr[col * 2 + 0], w1 = wr[col * 2 + 1];
    #pragma unroll
    for (int r = 0; r < 4; ++r) {
      float t = acc[r] + bcol;
      t = t > 0.f ? t : NEG_SLOPE * t;
      s0[r] = fmaf(t, w0, s0[r]);
      s1[r] = fmaf(t, w1, s1[r]);
    }
  }
  #pragma unroll
  for (int o = 1; o < 16; o <<= 1) {
    #pragma unroll
    for (int r = 0; r < 4; ++r) {
      s0[r] += __shfl_xor(s0[r], o, 16);
      s1[r] += __shfl_xor(s1[r], o, 16);
    }
  }
  if ((lane & 15) == 0) {
    #pragma unroll
    for (int r = 0; r < 4; ++r) {
      int row = base + (lane >> 4) * 4 + r;
      if (row < M) {
        P[row * 2 + 0] = s0[r];
        P[row * 2 + 1] = s1[r];
      }
    }
  }
}

__global__ __launch_bounds__(256) void k_fused(
    const float* __restrict__ mf, const float* __restrict__ fe,
    const u16x8* __restrict__ Wf, const float* __restrict__ bias,
    const float* __restrict__ wb, const float* __restrict__ Wo,
    float* __restrict__ T, float* __restrict__ Pm,
    const int* __restrict__ dst, int* __restrict__ cnt, int* __restrict__ slot,
    int M, int E, int Gg) {
  const int bid = blockIdx.x;
  // slot phase first: atomics issued early, LLC grinds while MFMA runs below
  for (int e = bid * 256 + threadIdx.x; e < E; e += gridDim.x * 256) {
    slot[e] = atomicAdd(&cnt[dst[e]], 1);
  }
  if (bid < Gg) {
    gemm_body<false>(mf, nullptr, Wf, bias, wb, T, M, bid);
  } else {
    gemm_body<true>(fe, mf, Wf, bias, Wo, Pm, M, bid - Gg);
  }
}

// ---------------- gather passes (4 lanes per node) ----------------
// T holds UNSCALED P; pass1 applies dis[s] per neighbor:
// T2[n] = dis[n]*(dis[n]*(dis[n]*T[n] + sum_s dis[s]*T[s]) + u)
__global__ __launch_bounds__(256) void k_gather1(
    const int* __restrict__ rp, const int* __restrict__ csr,
    const float* __restrict__ T, const float* __restrict__ dis,
    const float* __restrict__ uv, float* __restrict__ T2, int N) {
  int t = threadIdx.x;
  int n = blockIdx.x * 64 + (t >> 2);
  int l = t & 3;
  if (n >= N) return;
  int s0 = rp[n], s1 = rp[n + 1];
  float a0 = 0.f, a1 = 0.f;
  for (int j = s0 + l; j < s1; j += 4) {
    int s = csr[j];
    float ds = dis[s];
    float2 v = *(const float2*)&T[s * 2];
    a0 = fmaf(ds, v.x, a0); a1 = fmaf(ds, v.y, a1);
  }
  a0 += __shfl_xor(a0, 1, 4); a1 += __shfl_xor(a1, 1, 4);
  a0 += __shfl_xor(a0, 2, 4); a1 += __shfl_xor(a1, 2, 4);
  if (l == 0) {
    float d = dis[n];
    float2 tv = *(const float2*)&T[n * 2];
    T2[n * 2 + 0] = d * (d * (fmaf(d, tv.x, a0)) + uv[0]);
    T2[n * 2 + 1] = d * (d * (fmaf(d, tv.y, a1)) + uv[1]);
  }
}

// pass2 fused final: out[n] = (dis[n]*(T2[n]+sum T2[s]) + v) * (Pm[n] + bo)
__global__ __launch_bounds__(256) void k_gather2(
    const int* __restrict__ rp, const int* __restrict__ csr,
    const float* __restrict__ T2, const float* __restrict__ dis,
    const float* __restrict__ uv, const float* __restrict__ Pm,
    const float* __restrict__ bo, float* __restrict__ out, int N) {
  int t = threadIdx.x;
  int n = blockIdx.x * 64 + (t >> 2);
  int l = t & 3;
  if (n >= N) return;
  int s0 = rp[n], s1 = rp[n + 1];
  float a0 = 0.f, a1 = 0.f;
  for (int j = s0 + l; j < s1; j += 4) {
    int s = csr[j];
    float2 v = *(const float2*)&T2[s * 2];
    a0 += v.x; a1 += v.y;
  }
  a0 += __shfl_xor(a0, 1, 4); a1 += __shfl_xor(a1, 1, 4);
  a0 += __shfl_xor(a0, 2, 4); a1 += __shfl_xor(a1, 2, 4);
  if (l == 0) {
    float d = dis[n];
    float2 tv = *(const float2*)&T2[n * 2];
    float z0 = d * (tv.x + a0) + uv[2];
    float z1 = d * (tv.y + a1) + uv[3];
    out[n * 2 + 0] = z0 * (Pm[n * 2 + 0] + bo[0]);
    out[n * 2 + 1] = z1 * (Pm[n * 2 + 1] + bo[1]);
  }
}

extern "C" void kernel_launch(void* const* d_in, const int* in_sizes, int n_in,
                              void* d_out, int out_size, void* d_ws, size_t ws_size,
                              hipStream_t stream) {
  const float* mf  = (const float*)d_in[0];
  const float* fe  = (const float*)d_in[1];
  const int*   ei  = (const int*)d_in[2];
  const float* Win = (const float*)d_in[4];
  const float* bin = (const float*)d_in[5];
  const float* Wg1 = (const float*)d_in[6];
  const float* bg1 = (const float*)d_in[7];
  const float* Wg2 = (const float*)d_in[8];
  const float* bg2 = (const float*)d_in[9];
  const float* Wo  = (const float*)d_in[10];
  const float* bo  = (const float*)d_in[11];
  float* out = (float*)d_out;

  const int ED = 128;
  const int N = in_sizes[0] / ED;  // 50000
  const int E = in_sizes[3];       // 800000
  const int* src = ei;
  const int* dst = ei + E;

  char* ws = (char*)d_ws;
  size_t off = 0;
  auto carve = [&](size_t bytes) {
    char* p = ws + off;
    off += (bytes + 255) & ~(size_t)255;
    return p;
  };
  int*   cnt  = (int*)carve((size_t)N * 4);
  float* dis  = (float*)carve((size_t)N * 4);
  int*   rp   = (int*)carve((size_t)(N + 1) * 4);
  int*   slot = (int*)carve((size_t)E * 4);
  int*   csr  = (int*)carve((size_t)E * 4);
  int*   sums = (int*)carve(64 * 4);
  float* T    = (float*)carve((size_t)N * 2 * 4);
  float* T2   = (float*)carve((size_t)N * 2 * 4);
  float* Pm   = (float*)carve((size_t)N * 2 * 4);
  float* wb   = (float*)carve((size_t)HD * 2 * 4);
  float* uv   = (float*)carve(4 * 4);
  u16x8* Wf   = (u16x8*)carve((size_t)128 * 64 * 16); // 128 KB
  (void)ws_size; (void)n_in; (void)out_size;

  const int gN = (N + 255) / 256, gE = (E + 255) / 256;
  const int nb = (N + 1023) / 1024; // 49 <= 64
  const int Gg = (N + 63) / 64;     // 782 blocks per gemm role

  k_prep<<<33 + gN, 256, 0, stream>>>(Win, Wf, Wg1, Wg2, Wo, bg1, bg2, bo,
                                      wb, uv, cnt, N);
  k_fused<<<2 * Gg, 256, 0, stream>>>(mf, fe, Wf, bin, wb, Wo, T, Pm,
                                      dst, cnt, slot, N, E, Gg);
  k_scan1<<<nb, 1024, 0, stream>>>(cnt, rp, sums, dis, N);
  k_scan2<<<1, 64, 0, stream>>>(sums, nb);
  k_scan3<<<gN, 256, 0, stream>>>(rp, sums, N, E);
  k_fill<<<gE, 256, 0, stream>>>(src, dst, slot, rp, csr, E);
  k_gather1<<<Gg, 256, 0, stream>>>(rp, csr, T, dis, uv, T2, N);
  k_gather2<<<Gg, 256, 0, stream>>>(rp, csr, T2, dis, uv, Pm, bo, out, N);
}

// Round 6
// 118.833 us; speedup vs baseline: 5.7061x; 1.3004x over previous
//
#include <hip/hip_runtime.h>

// GCN forward: algebraic collapse + split-bf16 MFMA GEMMs + ATOMIC-FREE CSR build
// (2-level MSD counting sort, LDS atomics only) + L2-resident [N,2] gathers.
//   Z = Â(Â(X1@Wbig) + 1⊗u) + 1⊗v,  Â = D^-1/2 (A+I) D^-1/2
//   out = Z * (lrelu((F-MF)@W_in+b_in)@W_out + b_out)
// Sort: p1 partitions edges by dst>>8 into 196 buckets; p2 sorts each bucket by
// dst&0xFF in LDS, emitting rp, dis, csr directly. GEMMs ride as role-blocks on
// the p1scatter and p2 launches (independent work, real block-level overlap).

#define NEG_SLOPE 0.01f
constexpr int HD = 256;
constexpr int CHUNK = 8192; // edges per p1 block

typedef __bf16 bf16x8 __attribute__((ext_vector_type(8)));
typedef unsigned short u16x8 __attribute__((ext_vector_type(8)));
typedef float f32x4 __attribute__((ext_vector_type(4)));

__device__ inline void split1(float v, unsigned short& h, unsigned short& l) {
  unsigned u = __float_as_uint(v);
  unsigned hb = u & 0xFFFF0000u;
  float lf = v - __uint_as_float(hb);
  unsigned ul = __float_as_uint(lf);
  h = (unsigned short)(hb >> 16);
  l = (unsigned short)((ul + 0x7FFFu + ((ul >> 16) & 1u)) >> 16);
}

// ---------------- prep: W-split + consts ----------------
__global__ __launch_bounds__(256) void k_prep(
    const float* __restrict__ Win, u16x8* __restrict__ Wf,
    const float* __restrict__ Wg1, const float* __restrict__ Wg2,
    const float* __restrict__ Wo, const float* __restrict__ bg1,
    const float* __restrict__ bg2, const float* __restrict__ bo,
    float* __restrict__ wb, float* __restrict__ uv) {
  __shared__ float wt[256][2];
  const int bid = blockIdx.x, tid = threadIdx.x;
  if (bid < 32) {
    int f = bid * 4 + (tid >> 6);
    int lane = tid & 63;
    int nt = f >> 3, ks = (f >> 1) & 3, hl = f & 1;
    int n = nt * 16 + (lane & 15);
    int k0 = ks * 32 + (lane >> 4) * 8;
    u16x8 outv;
    #pragma unroll
    for (int j = 0; j < 8; ++j) {
      unsigned short h, l;
      split1(Win[(size_t)(k0 + j) * HD + n], h, l);
      outv[j] = hl ? l : h;
    }
    Wf[f * 64 + lane] = outv;
  } else {
    int r = tid;
    float s0 = 0.f, s1 = 0.f;
    for (int k = 0; k < 256; ++k) {
      float w = Wg2[r * 256 + k];
      s0 = fmaf(w, Wo[k * 2 + 0], s0);
      s1 = fmaf(w, Wo[k * 2 + 1], s1);
    }
    wt[r][0] = s0; wt[r][1] = s1;
    __syncthreads();
    float b0 = 0.f, b1 = 0.f;
    for (int k = 0; k < 256; ++k) {
      float w = Wg1[r * 256 + k];
      b0 = fmaf(w, wt[k][0], b0);
      b1 = fmaf(w, wt[k][1], b1);
    }
    wb[r * 2 + 0] = b0; wb[r * 2 + 1] = b1;
    if (r < 2) {
      float u = 0.f, v = 0.f;
      for (int k = 0; k < 256; ++k) {
        u = fmaf(bg1[k], wt[k][r], u);
        v = fmaf(bg2[k], Wo[k * 2 + r], v);
      }
      uv[r] = u;
      uv[2 + r] = v + bo[r];
    }
  }
}

// ---------------- sort pass 1: partition by dst>>8 ----------------
__global__ __launch_bounds__(256) void k_p1hist(const int* __restrict__ dst,
                                                int* __restrict__ gh, int E, int NB) {
  __shared__ int bins[256];
  const int t = threadIdx.x, b = blockIdx.x;
  bins[t] = 0;
  __syncthreads();
  const int e1 = min((b + 1) * CHUNK, E);
  for (int e = b * CHUNK + t; e < e1; e += 256)
    atomicAdd(&bins[dst[e] >> 8], 1);
  __syncthreads();
  gh[t * NB + b] = bins[t];
}

// per-bin exclusive prefix over blocks (256 blocks x 1 wave)
__global__ void k_p1scanA(int* __restrict__ gh, int* __restrict__ btot, int NB) {
  const int bin = blockIdx.x, lane = threadIdx.x;
  int carry = 0;
  for (int r = 0; r * 64 < NB; ++r) {
    int idx = r * 64 + lane;
    int v = (idx < NB) ? gh[bin * NB + idx] : 0;
    int incl = v;
    #pragma unroll
    for (int o = 1; o < 64; o <<= 1) {
      int tmp = __shfl_up(incl, o, 64);
      if (lane >= o) incl += tmp;
    }
    if (idx < NB) gh[bin * NB + idx] = carry + incl - v;
    carry += __shfl(incl, 63, 64);
  }
  if (lane == 0) btot[bin] = carry;
}

// exclusive scan of 256 bin totals -> bbase[0..256]
__global__ __launch_bounds__(256) void k_p1scanB(const int* __restrict__ btot,
                                                 int* __restrict__ bbase) {
  const int t = threadIdx.x, lane = t & 63, wid = t >> 6;
  int v = btot[t], incl = v;
  #pragma unroll
  for (int o = 1; o < 64; o <<= 1) {
    int tmp = __shfl_up(incl, o, 64);
    if (lane >= o) incl += tmp;
  }
  __shared__ int wsum[4];
  if (lane == 63) wsum[wid] = incl;
  __syncthreads();
  int woff = 0;
  for (int w = 0; w < wid; ++w) woff += wsum[w];
  bbase[t] = woff + incl - v;
  if (t == 255) bbase[256] = woff + incl;
}

// ---------------- MFMA GEMM body (one wave per 16-row strip, no LDS) ----------------
template <bool MASK>
__device__ __forceinline__ void gemm_body(
    const float* __restrict__ A, const float* __restrict__ A2,
    const u16x8* __restrict__ Wf, const float* __restrict__ bias,
    const float* __restrict__ wr, float* __restrict__ P, int M, int gbid) {
  const int tid = threadIdx.x;
  const int lane = tid & 63, wid = tid >> 6;
  const int base = gbid * 64 + wid * 16;
  int arow = base + (lane & 15);
  if (arow >= M) arow = M - 1;
  const int kb = (lane >> 4) * 8;
  const float* ap = A + (size_t)arow * 128 + kb;

  bf16x8 ahi[4], alo[4];
  #pragma unroll
  for (int ks = 0; ks < 4; ++ks) {
    float x[8];
    *(float4*)&x[0] = *(const float4*)(ap + ks * 32);
    *(float4*)&x[4] = *(const float4*)(ap + ks * 32 + 4);
    if constexpr (MASK) {
      const float* ap2 = A2 + (size_t)arow * 128 + kb;
      float y[8];
      *(float4*)&y[0] = *(const float4*)(ap2 + ks * 32);
      *(float4*)&y[4] = *(const float4*)(ap2 + ks * 32 + 4);
      #pragma unroll
      for (int j = 0; j < 8; ++j) x[j] -= y[j];
    }
    u16x8 h, l;
    #pragma unroll
    for (int j = 0; j < 8; ++j) {
      unsigned short hh, ll;
      split1(x[j], hh, ll);
      h[j] = hh; l[j] = ll;
    }
    ahi[ks] = __builtin_bit_cast(bf16x8, h);
    alo[ks] = __builtin_bit_cast(bf16x8, l);
  }

  float s0[4] = {0.f, 0.f, 0.f, 0.f}, s1[4] = {0.f, 0.f, 0.f, 0.f};
  #pragma unroll
  for (int nt = 0; nt < 16; ++nt) {
    f32x4 acc = {0.f, 0.f, 0.f, 0.f};
    #pragma unroll
    for (int ks = 0; ks < 4; ++ks) {
      bf16x8 bh = __builtin_bit_cast(bf16x8, Wf[((nt * 4 + ks) * 2 + 0) * 64 + lane]);
      bf16x8 bl = __builtin_bit_cast(bf16x8, Wf[((nt * 4 + ks) * 2 + 1) * 64 + lane]);
      acc = __builtin_amdgcn_mfma_f32_16x16x32_bf16(ahi[ks], bh, acc, 0, 0, 0);
      acc = __builtin_amdgcn_mfma_f32_16x16x32_bf16(alo[ks], bh, acc, 0, 0, 0);
      acc = __builtin_amdgcn_mfma_f32_16x16x32_bf16(ahi[ks], bl, acc, 0, 0, 0);
    }
    const int col = nt * 16 + (lane & 15);
    const float bcol = bias[col];
    const float w0 = wr[col * 2 + 0], w1 = wr[col * 2 + 1];
    #pragma unroll
    for (int r = 0; r < 4; ++r) {
      float t = acc[r] + bcol;
      t = t > 0.f ? t : NEG_SLOPE * t;
      s0[r] = fmaf(t, w0, s0[r]);
      s1[r] = fmaf(t, w1, s1[r]);
    }
  }
  #pragma unroll
  for (int o = 1; o < 16; o <<= 1) {
    #pragma unroll
    for (int r = 0; r < 4; ++r) {
      s0[r] += __shfl_xor(s0[r], o, 16);
      s1[r] += __shfl_xor(s1[r], o, 16);
    }
  }
  if ((lane & 15) == 0) {
    #pragma unroll
    for (int r = 0; r < 4; ++r) {
      int row = base + (lane >> 4) * 4 + r;
      if (row < M) {
        P[row * 2 + 0] = s0[r];
        P[row * 2 + 1] = s1[r];
      }
    }
  }
}

// ---------------- p1 scatter (bucket partition) + main GEMM role-blocks ----------------
__global__ __launch_bounds__(256) void k_scatter_gemm(
    const int* __restrict__ src, const int* __restrict__ dst,
    const int* __restrict__ gh, const int* __restrict__ bbase,
    unsigned* __restrict__ packed, int E, int NB,
    const float* __restrict__ mf, const u16x8* __restrict__ Wf,
    const float* __restrict__ bi, const float* __restrict__ wb,
    float* __restrict__ T, int M) {
  __shared__ int cur[256];
  const int t = threadIdx.x;
  if ((int)blockIdx.x < NB) {
    const int b = blockIdx.x;
    cur[t] = bbase[t] + gh[t * NB + b]; // global start for (bin t, block b)
    __syncthreads();
    const int e1 = min((b + 1) * CHUNK, E);
    for (int e = b * CHUNK + t; e < e1; e += 256) {
      int d = dst[e];
      int s = src[e];
      int pos = atomicAdd(&cur[d >> 8], 1); // LDS atomic, order-arbitrary (OK)
      packed[pos] = ((unsigned)d << 16) | (unsigned)s;
    }
  } else {
    gemm_body<false>(mf, nullptr, Wf, bi, wb, T, M, blockIdx.x - NB);
  }
}

// ---------------- p2: per-bucket sort by dst&0xFF -> rp, dis, csr; + mask GEMM ----------------
__global__ __launch_bounds__(256) void k_p2_gemm(
    const unsigned* __restrict__ packed, const int* __restrict__ bbase,
    int* __restrict__ rp, float* __restrict__ dis, int* __restrict__ csr, int N,
    const float* __restrict__ fe, const float* __restrict__ mf,
    const u16x8* __restrict__ Wf, const float* __restrict__ bi,
    const float* __restrict__ Wo, float* __restrict__ Pm, int M, int NP2) {
  __shared__ int cnt[256];
  __shared__ int wsum[4];
  const int t = threadIdx.x;
  if ((int)blockIdx.x < NP2) {
    const int B = blockIdx.x;
    const int base = bbase[B], end = bbase[B + 1];
    cnt[t] = 0;
    __syncthreads();
    for (int i = base + t; i < end; i += 256)
      atomicAdd(&cnt[(packed[i] >> 16) & 0xFF], 1);
    __syncthreads();
    // exclusive scan of cnt -> off (in registers)
    const int lane = t & 63, wid = t >> 6;
    int v = cnt[t], incl = v;
    #pragma unroll
    for (int o = 1; o < 64; o <<= 1) {
      int tmp = __shfl_up(incl, o, 64);
      if (lane >= o) incl += tmp;
    }
    if (lane == 63) wsum[wid] = incl;
    __syncthreads();
    int woff = 0;
    for (int w = 0; w < wid; ++w) woff += wsum[w];
    const int off = woff + incl - v;
    const int node = B * 256 + t;
    if (node < N) {
      rp[node] = base + off;
      dis[node] = rsqrtf((float)(v + 1));
    } else if (node == N) {
      rp[N] = base + off; // cnt above max dst is 0 -> this equals E
    }
    __syncthreads();
    cnt[t] = off; // cursor
    __syncthreads();
    for (int i = base + t; i < end; i += 256) {
      unsigned pv = packed[i];
      int pos = base + atomicAdd(&cnt[(pv >> 16) & 0xFF], 1);
      csr[pos] = (int)(pv & 0xFFFFu);
    }
  } else {
    gemm_body<true>(fe, mf, Wf, bi, Wo, Pm, M, blockIdx.x - NP2);
  }
}

// ---------------- gather passes (4 lanes per node) ----------------
// T holds UNSCALED P; pass1:
// T2[n] = dis[n]*(dis[n]*(dis[n]*T[n] + sum_s dis[s]*T[s]) + u)
__global__ __launch_bounds__(256) void k_gather1(
    const int* __restrict__ rp, const int* __restrict__ csr,
    const float* __restrict__ T, const float* __restrict__ dis,
    const float* __restrict__ uv, float* __restrict__ T2, int N) {
  int t = threadIdx.x;
  int n = blockIdx.x * 64 + (t >> 2);
  int l = t & 3;
  if (n >= N) return;
  int s0 = rp[n], s1 = rp[n + 1];
  float a0 = 0.f, a1 = 0.f;
  for (int j = s0 + l; j < s1; j += 4) {
    int s = csr[j];
    float ds = dis[s];
    float2 v = *(const float2*)&T[s * 2];
    a0 = fmaf(ds, v.x, a0); a1 = fmaf(ds, v.y, a1);
  }
  a0 += __shfl_xor(a0, 1, 4); a1 += __shfl_xor(a1, 1, 4);
  a0 += __shfl_xor(a0, 2, 4); a1 += __shfl_xor(a1, 2, 4);
  if (l == 0) {
    float d = dis[n];
    float2 tv = *(const float2*)&T[n * 2];
    T2[n * 2 + 0] = d * (d * (fmaf(d, tv.x, a0)) + uv[0]);
    T2[n * 2 + 1] = d * (d * (fmaf(d, tv.y, a1)) + uv[1]);
  }
}

// pass2 fused final: out[n] = (dis[n]*(T2[n]+sum T2[s]) + v) * (Pm[n] + bo)
__global__ __launch_bounds__(256) void k_gather2(
    const int* __restrict__ rp, const int* __restrict__ csr,
    const float* __restrict__ T2, const float* __restrict__ dis,
    const float* __restrict__ uv, const float* __restrict__ Pm,
    const float* __restrict__ bo, float* __restrict__ out, int N) {
  int t = threadIdx.x;
  int n = blockIdx.x * 64 + (t >> 2);
  int l = t & 3;
  if (n >= N) return;
  int s0 = rp[n], s1 = rp[n + 1];
  float a0 = 0.f, a1 = 0.f;
  for (int j = s0 + l; j < s1; j += 4) {
    int s = csr[j];
    float2 v = *(const float2*)&T2[s * 2];
    a0 += v.x; a1 += v.y;
  }
  a0 += __shfl_xor(a0, 1, 4); a1 += __shfl_xor(a1, 1, 4);
  a0 += __shfl_xor(a0, 2, 4); a1 += __shfl_xor(a1, 2, 4);
  if (l == 0) {
    float d = dis[n];
    float2 tv = *(const float2*)&T2[n * 2];
    float z0 = d * (tv.x + a0) + uv[2];
    float z1 = d * (tv.y + a1) + uv[3];
    out[n * 2 + 0] = z0 * (Pm[n * 2 + 0] + bo[0]);
    out[n * 2 + 1] = z1 * (Pm[n * 2 + 1] + bo[1]);
  }
}

extern "C" void kernel_launch(void* const* d_in, const int* in_sizes, int n_in,
                              void* d_out, int out_size, void* d_ws, size_t ws_size,
                              hipStream_t stream) {
  const float* mf  = (const float*)d_in[0];
  const float* fe  = (const float*)d_in[1];
  const int*   ei  = (const int*)d_in[2];
  const float* Win = (const float*)d_in[4];
  const float* bin = (const float*)d_in[5];
  const float* Wg1 = (const float*)d_in[6];
  const float* bg1 = (const float*)d_in[7];
  const float* Wg2 = (const float*)d_in[8];
  const float* bg2 = (const float*)d_in[9];
  const float* Wo  = (const float*)d_in[10];
  const float* bo  = (const float*)d_in[11];
  float* out = (float*)d_out;

  const int ED = 128;
  const int N = in_sizes[0] / ED;  // 50000
  const int E = in_sizes[3];       // 800000
  const int* src = ei;
  const int* dst = ei + E;

  char* ws = (char*)d_ws;
  size_t off = 0;
  auto carve = [&](size_t bytes) {
    char* p = ws + off;
    off += (bytes + 255) & ~(size_t)255;
    return p;
  };
  const int NB  = (E + CHUNK - 1) / CHUNK;        // 98 p1 blocks
  const int NP2 = (N + 255) / 256;                // 196 buckets
  int*      gh     = (int*)carve((size_t)256 * NB * 4);
  int*      btot   = (int*)carve(256 * 4);
  int*      bbase  = (int*)carve(257 * 4);
  unsigned* packed = (unsigned*)carve((size_t)E * 4);
  int*      csr    = (int*)carve((size_t)E * 4);
  int*      rp     = (int*)carve((size_t)(N + 1) * 4);
  float*    dis    = (float*)carve((size_t)N * 4);
  float*    T      = (float*)carve((size_t)N * 2 * 4);
  float*    T2     = (float*)carve((size_t)N * 2 * 4);
  float*    Pm     = (float*)carve((size_t)N * 2 * 4);
  float*    wb     = (float*)carve((size_t)HD * 2 * 4);
  float*    uv     = (float*)carve(4 * 4);
  u16x8*    Wf     = (u16x8*)carve((size_t)128 * 64 * 16); // 128 KB
  (void)ws_size; (void)n_in; (void)out_size;

  const int Gg = (N + 63) / 64; // 782 blocks per GEMM role

  // 1. prep: Wf split + Wbig/uv consts
  k_prep<<<33, 256, 0, stream>>>(Win, Wf, Wg1, Wg2, Wo, bg1, bg2, bo, wb, uv);
  // 2-4. sort pass 1: hist + scans
  k_p1hist<<<NB, 256, 0, stream>>>(dst, gh, E, NB);
  k_p1scanA<<<256, 64, 0, stream>>>(gh, btot, NB);
  k_p1scanB<<<1, 256, 0, stream>>>(btot, bbase);
  // 5. bucket partition + main GEMM (independent role-blocks)
  k_scatter_gemm<<<NB + Gg, 256, 0, stream>>>(src, dst, gh, bbase, packed, E, NB,
                                              mf, Wf, bin, wb, T, N);
  // 6. per-bucket sort -> rp/dis/csr + mask GEMM (independent role-blocks)
  k_p2_gemm<<<NP2 + Gg, 256, 0, stream>>>(packed, bbase, rp, dis, csr, N,
                                          fe, mf, Wf, bin, Wo, Pm, N, NP2);
  // 7-8. gathers
  k_gather1<<<Gg, 256, 0, stream>>>(rp, csr, T, dis, uv, T2, N);
  k_gather2<<<Gg, 256, 0, stream>>>(rp, csr, T2, dis, uv, Pm, bo, out, N);
}

// Round 7
// 97.632 us; speedup vs baseline: 6.9451x; 1.2171x over previous
//
#include <hip/hip_runtime.h>

// GCN forward: algebraic collapse + merged split-bf16 MFMA GEMM (LDS-staged B) +
// atomic-free-ish CSR build (bucket sort, LDS atomics + per-block range reservation)
// + L2-resident [N,2] gathers. 5 launches:
//   k_prep     : Wf split + Wbig/u/v consts + zero(cur)
//   k_scatter  : per-chunk LDS hist -> reserve bucket ranges -> strided bucket write
//   k_p2_gemm  : per-bucket sort -> rp/dis/csr  ||  merged main+mask GEMM role-blocks
//   k_gather1  : T2 = dis*(Â-inner(P) + u)   (one float4 random read per edge)
//   k_gather2  : out = (Â-inner(T2) + v) * (Pm + bo)
// Math:  Z = Â(Â(X1@Wbig) + 1⊗u) + 1⊗v,  Â = D^-1/2 (A+I) D^-1/2
//        out = Z * (lrelu((F-MF)@W_in+b_in)@W_out + b_out)

#define NEG_SLOPE 0.01f
constexpr int HD = 256;
constexpr int CHUNK = 2048;       // edges per scatter block
constexpr int EPB = CHUNK / 256;  // 8 edges per thread
constexpr int BSTRIDE = 16384;    // packed bucket capacity (expected ~4082 +- 64)

typedef __bf16 bf16x8 __attribute__((ext_vector_type(8)));
typedef unsigned short u16x8 __attribute__((ext_vector_type(8)));
typedef float f32x4 __attribute__((ext_vector_type(4)));

// split fp32 -> bf16 hi (truncate) + bf16 lo (RNE of remainder)
__device__ inline void split1(float v, unsigned short& h, unsigned short& l) {
  unsigned u = __float_as_uint(v);
  unsigned hb = u & 0xFFFF0000u;
  float lf = v - __uint_as_float(hb);
  unsigned ul = __float_as_uint(lf);
  h = (unsigned short)(hb >> 16);
  l = (unsigned short)((ul + 0x7FFFu + ((ul >> 16) & 1u)) >> 16);
}

// ---------------- prep: W-split + consts + zero(cur) ----------------
__global__ __launch_bounds__(256) void k_prep(
    const float* __restrict__ Win, u16x8* __restrict__ Wf,
    const float* __restrict__ Wg1, const float* __restrict__ Wg2,
    const float* __restrict__ Wo, const float* __restrict__ bg1,
    const float* __restrict__ bg2, const float* __restrict__ bo,
    float* __restrict__ wb, float* __restrict__ uv, int* __restrict__ cur) {
  __shared__ float wt[256][2];
  const int bid = blockIdx.x, tid = threadIdx.x;
  if (bid < 32) {
    // fragment f: ntile=f>>3, kstep=(f>>1)&3, hl=f&1; lane's 8 elems:
    //   Win[kstep*32 + (lane>>4)*8 + j][ntile*16 + (lane&15)]
    int f = bid * 4 + (tid >> 6);
    int lane = tid & 63;
    int nt = f >> 3, ks = (f >> 1) & 3, hl = f & 1;
    int n = nt * 16 + (lane & 15);
    int k0 = ks * 32 + (lane >> 4) * 8;
    u16x8 outv;
    #pragma unroll
    for (int j = 0; j < 8; ++j) {
      unsigned short h, l;
      split1(Win[(size_t)(k0 + j) * HD + n], h, l);
      outv[j] = hl ? l : h;
    }
    Wf[f * 64 + lane] = outv;
  } else if (bid == 32) {
    int r = tid;
    float s0 = 0.f, s1 = 0.f;
    for (int k = 0; k < 256; ++k) {
      float w = Wg2[r * 256 + k];
      s0 = fmaf(w, Wo[k * 2 + 0], s0);
      s1 = fmaf(w, Wo[k * 2 + 1], s1);
    }
    wt[r][0] = s0; wt[r][1] = s1;
    __syncthreads();
    float b0 = 0.f, b1 = 0.f;
    for (int k = 0; k < 256; ++k) {
      float w = Wg1[r * 256 + k];
      b0 = fmaf(w, wt[k][0], b0);
      b1 = fmaf(w, wt[k][1], b1);
    }
    wb[r * 2 + 0] = b0; wb[r * 2 + 1] = b1;
    if (r < 2) {
      float u = 0.f, v = 0.f;
      for (int k = 0; k < 256; ++k) {
        u = fmaf(bg1[k], wt[k][r], u);
        v = fmaf(bg2[k], Wo[k * 2 + r], v);
      }
      uv[r] = u;             // u[c]
      uv[2 + r] = v + bo[r]; // v[c]
    }
  } else {
    cur[tid] = 0;
  }
}

// ---------------- scatter: hist + reserve + strided bucket write ----------------
__global__ __launch_bounds__(256) void k_scatter(
    const int* __restrict__ src, const int* __restrict__ dst,
    int* __restrict__ cur, unsigned* __restrict__ packed, int E) {
  __shared__ int bins[256];
  __shared__ int lcur[256];
  const int t = threadIdx.x, b = blockIdx.x;
  bins[t] = 0;
  __syncthreads();
  int dl[EPB], sl[EPB];
  const int e0 = b * CHUNK;
  #pragma unroll
  for (int i = 0; i < EPB; ++i) {
    int e = e0 + i * 256 + t;
    if (e < E) {
      dl[i] = dst[e];
      sl[i] = src[e];
      atomicAdd(&bins[dl[i] >> 8], 1);
    } else {
      dl[i] = -1;
    }
  }
  __syncthreads();
  lcur[t] = atomicAdd(&cur[t], bins[t]); // reserve this block's range in bucket t
  __syncthreads();
  #pragma unroll
  for (int i = 0; i < EPB; ++i) {
    if (dl[i] >= 0) {
      int bin = dl[i] >> 8;
      int pos = atomicAdd(&lcur[bin], 1); // LDS cursor; order-arbitrary (sum commutes)
      packed[(size_t)bin * BSTRIDE + pos] = ((unsigned)dl[i] << 16) | (unsigned)sl[i];
    }
  }
}

// ---------------- merged main+mask GEMM (LDS-staged B, one wave / 16-row strip) ----
__device__ __forceinline__ void gemm_both(
    const float* __restrict__ mf, const float* __restrict__ fe,
    const u16x8* __restrict__ Wf, const float* __restrict__ bi,
    const float* __restrict__ wb, const float* __restrict__ Wo,
    float4* __restrict__ q, float* __restrict__ Pm, int M, int gbid,
    u16x8* stage) {
  const int tid = threadIdx.x;
  const int lane = tid & 63, wid = tid >> 6;
  const int base = gbid * 64 + wid * 16;
  int arow = base + (lane & 15);
  if (arow >= M) arow = M - 1;
  const int kb = (lane >> 4) * 8;
  const float* ap = mf + (size_t)arow * 128 + kb;
  const float* fp = fe + (size_t)arow * 128 + kb;

  // A fragments for both branches: main = MF, mask = FE - MF (hi/lo split each)
  bf16x8 ahi[4], alo[4], mhi[4], mlo[4];
  #pragma unroll
  for (int ks = 0; ks < 4; ++ks) {
    float x[8], y[8];
    *(float4*)&x[0] = *(const float4*)(ap + ks * 32);
    *(float4*)&x[4] = *(const float4*)(ap + ks * 32 + 4);
    *(float4*)&y[0] = *(const float4*)(fp + ks * 32);
    *(float4*)&y[4] = *(const float4*)(fp + ks * 32 + 4);
    u16x8 h, l, h2, l2;
    #pragma unroll
    for (int j = 0; j < 8; ++j) {
      unsigned short hh, ll;
      split1(x[j], hh, ll);      h[j] = hh;  l[j] = ll;
      split1(y[j] - x[j], hh, ll); h2[j] = hh; l2[j] = ll;
    }
    ahi[ks] = __builtin_bit_cast(bf16x8, h);
    alo[ks] = __builtin_bit_cast(bf16x8, l);
    mhi[ks] = __builtin_bit_cast(bf16x8, h2);
    mlo[ks] = __builtin_bit_cast(bf16x8, l2);
  }

  float s0[4] = {0,0,0,0}, s1[4] = {0,0,0,0};
  float t0[4] = {0,0,0,0}, t1[4] = {0,0,0,0};
  for (int nt = 0; nt < 16; ++nt) {
    __syncthreads(); // protect previous iteration's stage reads
    stage[tid * 2 + 0] = Wf[nt * 512 + tid * 2 + 0]; // 8KB: this nt's 8 frags
    stage[tid * 2 + 1] = Wf[nt * 512 + tid * 2 + 1];
    __syncthreads();
    f32x4 aM = {0,0,0,0}, aK = {0,0,0,0};
    #pragma unroll
    for (int ks = 0; ks < 4; ++ks) {
      bf16x8 bh = __builtin_bit_cast(bf16x8, stage[(ks * 2 + 0) * 64 + lane]);
      bf16x8 bl = __builtin_bit_cast(bf16x8, stage[(ks * 2 + 1) * 64 + lane]);
      aM = __builtin_amdgcn_mfma_f32_16x16x32_bf16(ahi[ks], bh, aM, 0, 0, 0);
      aM = __builtin_amdgcn_mfma_f32_16x16x32_bf16(alo[ks], bh, aM, 0, 0, 0);
      aM = __builtin_amdgcn_mfma_f32_16x16x32_bf16(ahi[ks], bl, aM, 0, 0, 0);
      aK = __builtin_amdgcn_mfma_f32_16x16x32_bf16(mhi[ks], bh, aK, 0, 0, 0);
      aK = __builtin_amdgcn_mfma_f32_16x16x32_bf16(mlo[ks], bh, aK, 0, 0, 0);
      aK = __builtin_amdgcn_mfma_f32_16x16x32_bf16(mhi[ks], bl, aK, 0, 0, 0);
    }
    // D frag: col = lane&15, row = (lane>>4)*4 + r
    const int col = nt * 16 + (lane & 15);
    const float bc = bi[col];
    const float w0 = wb[col * 2 + 0], w1 = wb[col * 2 + 1];
    const float v0 = Wo[col * 2 + 0], v1 = Wo[col * 2 + 1];
    #pragma unroll
    for (int r = 0; r < 4; ++r) {
      float a = aM[r] + bc; a = a > 0.f ? a : NEG_SLOPE * a;
      s0[r] = fmaf(a, w0, s0[r]); s1[r] = fmaf(a, w1, s1[r]);
      float m = aK[r] + bc; m = m > 0.f ? m : NEG_SLOPE * m;
      t0[r] = fmaf(m, v0, t0[r]); t1[r] = fmaf(m, v1, t1[r]);
    }
  }
  #pragma unroll
  for (int o = 1; o < 16; o <<= 1) {
    #pragma unroll
    for (int r = 0; r < 4; ++r) {
      s0[r] += __shfl_xor(s0[r], o, 16); s1[r] += __shfl_xor(s1[r], o, 16);
      t0[r] += __shfl_xor(t0[r], o, 16); t1[r] += __shfl_xor(t1[r], o, 16);
    }
  }
  if ((lane & 15) == 0) {
    #pragma unroll
    for (int r = 0; r < 4; ++r) {
      int row = base + (lane >> 4) * 4 + r;
      if (row < M) {
        float* qf = (float*)&q[row];
        qf[1] = s0[r]; // P0 (unscaled); qf[0]=dis written by p2 role-blocks
        qf[2] = s1[r]; // P1
        Pm[row * 2 + 0] = t0[r];
        Pm[row * 2 + 1] = t1[r];
      }
    }
  }
}

// ---------------- p2: per-bucket sort -> rp/dis/csr  ||  GEMM role-blocks --------
__global__ __launch_bounds__(256) void k_p2_gemm(
    const unsigned* __restrict__ packed, const int* __restrict__ cur,
    int* __restrict__ rp, float4* __restrict__ q, int* __restrict__ csr, int N,
    const float* __restrict__ mf, const float* __restrict__ fe,
    const u16x8* __restrict__ Wf, const float* __restrict__ bi,
    const float* __restrict__ wb, const float* __restrict__ Wo,
    float* __restrict__ Pm, int NP2) {
  __shared__ u16x8 stage[512]; // 8KB (gemm role)
  __shared__ int cnt[256];
  __shared__ int sc[256];
  __shared__ int wsum[4];
  const int t = threadIdx.x;
  if ((int)blockIdx.x >= NP2) {
    gemm_both(mf, fe, Wf, bi, wb, Wo, q, Pm, N, blockIdx.x - NP2, stage);
    return;
  }
  const int B = blockIdx.x;
  const int lane = t & 63, wid = t >> 6;
  // global bucket base = exclusive scan of cur[0..255] at index B
  int tot = cur[t], incl = tot;
  #pragma unroll
  for (int o = 1; o < 64; o <<= 1) {
    int tmp = __shfl_up(incl, o, 64);
    if (lane >= o) incl += tmp;
  }
  if (lane == 63) wsum[wid] = incl;
  __syncthreads();
  int woff = 0;
  for (int w = 0; w < wid; ++w) woff += wsum[w];
  sc[t] = woff + incl - tot;
  __syncthreads();
  const int base = sc[B];
  const int ecnt = cur[B];
  const unsigned* pk = packed + (size_t)B * BSTRIDE;
  // per-node histogram (dst & 0xFF)
  cnt[t] = 0;
  __syncthreads();
  for (int i = t; i < ecnt; i += 256)
    atomicAdd(&cnt[(pk[i] >> 16) & 0xFF], 1);
  __syncthreads();
  int v = cnt[t];
  incl = v;
  #pragma unroll
  for (int o = 1; o < 64; o <<= 1) {
    int tmp = __shfl_up(incl, o, 64);
    if (lane >= o) incl += tmp;
  }
  if (lane == 63) wsum[wid] = incl;
  __syncthreads();
  woff = 0;
  for (int w = 0; w < wid; ++w) woff += wsum[w];
  const int off = woff + incl - v;
  const int node = B * 256 + t;
  if (node < N) {
    rp[node] = base + off;
    ((float*)&q[node])[0] = rsqrtf((float)(v + 1)); // dis; +1 self-loop
  } else if (node == N) {
    rp[N] = base + off; // == E
  }
  __syncthreads();
  cnt[t] = off;
  __syncthreads();
  for (int i = t; i < ecnt; i += 256) {
    unsigned pv = pk[i];
    int pos = base + atomicAdd(&cnt[(pv >> 16) & 0xFF], 1);
    csr[pos] = (int)(pv & 0xFFFFu);
  }
}

// ---------------- gather passes (4 lanes per node) ----------------
// q[n] = {dis, P0, P1, -};  T2[n] = dis[n]*(dis[n]*(dis[n]*P[n] + sum dis[s]P[s]) + u)
__global__ __launch_bounds__(256) void k_gather1(
    const int* __restrict__ rp, const int* __restrict__ csr,
    const float4* __restrict__ q, const float* __restrict__ uv,
    float* __restrict__ T2, int N) {
  int t = threadIdx.x;
  int n = blockIdx.x * 64 + (t >> 2);
  int l = t & 3;
  if (n >= N) return;
  int s0 = rp[n], s1 = rp[n + 1];
  float a0 = 0.f, a1 = 0.f;
  for (int j = s0 + l; j < s1; j += 4) {
    float4 qq = q[csr[j]];
    a0 = fmaf(qq.x, qq.y, a0);
    a1 = fmaf(qq.x, qq.z, a1);
  }
  a0 += __shfl_xor(a0, 1, 4); a1 += __shfl_xor(a1, 1, 4);
  a0 += __shfl_xor(a0, 2, 4); a1 += __shfl_xor(a1, 2, 4);
  if (l == 0) {
    float4 qn = q[n];
    float d = qn.x;
    T2[n * 2 + 0] = d * (d * fmaf(d, qn.y, a0) + uv[0]);
    T2[n * 2 + 1] = d * (d * fmaf(d, qn.z, a1) + uv[1]);
  }
}

// out[n] = (dis[n]*(T2[n] + sum T2[s]) + v) * (Pm[n] + bo)
__global__ __launch_bounds__(256) void k_gather2(
    const int* __restrict__ rp, const int* __restrict__ csr,
    const float* __restrict__ T2, const float4* __restrict__ q,
    const float* __restrict__ uv, const float* __restrict__ Pm,
    const float* __restrict__ bo, float* __restrict__ out, int N) {
  int t = threadIdx.x;
  int n = blockIdx.x * 64 + (t >> 2);
  int l = t & 3;
  if (n >= N) return;
  int s0 = rp[n], s1 = rp[n + 1];
  float a0 = 0.f, a1 = 0.f;
  for (int j = s0 + l; j < s1; j += 4) {
    int s = csr[j];
    float2 v = *(const float2*)&T2[s * 2];
    a0 += v.x; a1 += v.y;
  }
  a0 += __shfl_xor(a0, 1, 4); a1 += __shfl_xor(a1, 1, 4);
  a0 += __shfl_xor(a0, 2, 4); a1 += __shfl_xor(a1, 2, 4);
  if (l == 0) {
    float d = q[n].x;
    float2 tv = *(const float2*)&T2[n * 2];
    float z0 = d * (tv.x + a0) + uv[2];
    float z1 = d * (tv.y + a1) + uv[3];
    out[n * 2 + 0] = z0 * (Pm[n * 2 + 0] + bo[0]);
    out[n * 2 + 1] = z1 * (Pm[n * 2 + 1] + bo[1]);
  }
}

extern "C" void kernel_launch(void* const* d_in, const int* in_sizes, int n_in,
                              void* d_out, int out_size, void* d_ws, size_t ws_size,
                              hipStream_t stream) {
  const float* mf  = (const float*)d_in[0];
  const float* fe  = (const float*)d_in[1];
  const int*   ei  = (const int*)d_in[2];
  const float* Win = (const float*)d_in[4];
  const float* bin = (const float*)d_in[5];
  const float* Wg1 = (const float*)d_in[6];
  const float* bg1 = (const float*)d_in[7];
  const float* Wg2 = (const float*)d_in[8];
  const float* bg2 = (const float*)d_in[9];
  const float* Wo  = (const float*)d_in[10];
  const float* bo  = (const float*)d_in[11];
  float* out = (float*)d_out;

  const int ED = 128;
  const int N = in_sizes[0] / ED;  // 50000
  const int E = in_sizes[3];       // 800000
  const int* src = ei;
  const int* dst = ei + E;

  char* ws = (char*)d_ws;
  size_t off = 0;
  auto carve = [&](size_t bytes) {
    char* p = ws + off;
    off += (bytes + 255) & ~(size_t)255;
    return p;
  };
  int*      cur    = (int*)carve(256 * 4);
  unsigned* packed = (unsigned*)carve((size_t)256 * BSTRIDE * 4); // 16 MB
  int*      csr    = (int*)carve((size_t)E * 4);
  int*      rp     = (int*)carve((size_t)(N + 1) * 4);
  float4*   q      = (float4*)carve((size_t)N * 16);   // {dis, P0, P1, -}
  float*    T2     = (float*)carve((size_t)N * 2 * 4);
  float*    Pm     = (float*)carve((size_t)N * 2 * 4);
  float*    wb     = (float*)carve((size_t)HD * 2 * 4);
  float*    uv     = (float*)carve(4 * 4);
  u16x8*    Wf     = (u16x8*)carve((size_t)128 * 64 * 16); // 128 KB
  (void)ws_size; (void)n_in; (void)out_size;

  const int NB  = (E + CHUNK - 1) / CHUNK; // 391 scatter blocks
  const int NP2 = (N + 255) / 256;         // 196 buckets
  const int Gg  = (N + 63) / 64;           // 782 GEMM role blocks

  k_prep<<<34, 256, 0, stream>>>(Win, Wf, Wg1, Wg2, Wo, bg1, bg2, bo, wb, uv, cur);
  k_scatter<<<NB, 256, 0, stream>>>(src, dst, cur, packed, E);
  k_p2_gemm<<<NP2 + Gg, 256, 0, stream>>>(packed, cur, rp, q, csr, N,
                                          mf, fe, Wf, bin, wb, Wo, Pm, NP2);
  k_gather1<<<Gg, 256, 0, stream>>>(rp, csr, q, uv, T2, N);
  k_gather2<<<Gg, 256, 0, stream>>>(rp, csr, T2, q, uv, Pm, bo, out, N);
}